// Round 15
// baseline (217.030 us; speedup 1.0000x reference)
//
#include <hip/hip_runtime.h>
#include <hip/hip_fp16.h>

#define H 1024
#define E 8
#define TT 8192  // tokens = B*S

typedef __attribute__((ext_vector_type(8))) short bf16x8;
typedef __attribute__((ext_vector_type(4))) float f32x4;

__device__ __forceinline__ unsigned short f2bf(float f) {
  unsigned int u = __float_as_uint(f);
  u += 0x7fffu + ((u >> 16) & 1u);
  return (unsigned short)(u >> 16);
}

// LDS tile addressing: rows of 32 bf16 = 64B = 4 chunks of 16B.
// XOR swizzle chunk' = c ^ ((row>>1)&3): conflict-free writes AND mfma b128 reads (0 conflicts, R3-R14).
__device__ __forceinline__ int swz(int row, int c) {
  return (row << 5) | (((c ^ (row >> 1)) & 3) << 3);
}

// async global->LDS, 16B per lane; LDS dest = wave-uniform base + lane*16 (linear).
__device__ __forceinline__ void gld16(void* lds, const void* g) {
  __builtin_amdgcn_global_load_lds((const __attribute__((address_space(1))) void*)g,
                                   (__attribute__((address_space(3))) void*)lds, 16, 0, 0);
}

// Fused roots: blocks [0,1024) = cast_w1 (+part partials, +init cnt/psum); blocks [1024,9216) = stats.
__global__ __launch_bounds__(256) void k_pre(const float* __restrict__ w1, const float* __restrict__ lsc,
                                             const float* __restrict__ lbi, const float* __restrict__ x,
                                             unsigned short* __restrict__ w1h, unsigned short* __restrict__ w1l,
                                             float* __restrict__ part, float2* __restrict__ stats,
                                             unsigned short* __restrict__ xb, int* __restrict__ cnt,
                                             double* __restrict__ psum) {
  int blk = blockIdx.x;
  int t = threadIdx.x;
  if (blk < 1024) {
    // ---- cast_w1 ----
    __shared__ float tile[32][33];
    __shared__ float red[8][33];
    int kb = (blk & 31) << 5, nb = (blk >> 5) << 5;
    int cc = t & 31, rr = t >> 5;
    if (blk == 0 && t < E) { cnt[t] = 0; psum[t] = 0.0; }
#pragma unroll
    for (int r = 0; r < 4; ++r) {
      int k = kb + rr + (r << 3);
      tile[rr + (r << 3)][cc] = w1[(size_t)k * H + nb + cc];
    }
    __syncthreads();
    float pp = 0.f;
#pragma unroll
    for (int r = 0; r < 4; ++r) {
      int kk = rr + (r << 3);
      pp = fmaf(lbi[kb + kk], tile[kk][cc], pp);
    }
    red[rr][cc] = pp;
    float scale = lsc[kb + cc];
    __syncthreads();
    if (rr == 0) {
      float s = 0.f;
#pragma unroll
      for (int j = 0; j < 8; ++j) s += red[j][cc];
      part[(blk & 31) * H + nb + cc] = s;
    }
#pragma unroll
    for (int r = 0; r < 4; ++r) {
      int n = nb + rr + (r << 3);
      float v = tile[cc][rr + (r << 3)] * scale;
      unsigned short h = f2bf(v);
      float hv = __uint_as_float((unsigned)h << 16);
      unsigned short l = f2bf(v - hv);
      w1h[(size_t)n * H + kb + cc] = h;
      w1l[(size_t)n * H + kb + cc] = l;
    }
  } else {
    // ---- stats ----
    int tok = blk - 1024;
    const float4 v = *reinterpret_cast<const float4*>(&x[(size_t)tok * H + (t << 2)]);
    float s = v.x + v.y + v.z + v.w;
    float ss = v.x * v.x + v.y * v.y + v.z * v.z + v.w * v.w;
#pragma unroll
    for (int off = 32; off; off >>= 1) { s += __shfl_down(s, off); ss += __shfl_down(ss, off); }
    __shared__ float red2[4][2];
    int lane = t & 63, wv = t >> 6;
    if (lane == 0) { red2[wv][0] = s; red2[wv][1] = ss; }
    __syncthreads();
    float fs = red2[0][0] + red2[1][0] + red2[2][0] + red2[3][0];
    float fss = red2[0][1] + red2[1][1] + red2[2][1] + red2[3][1];
    float mean = fs * (1.0f / H);
    float var = fss * (1.0f / H) - mean * mean;
    float rstd = rsqrtf(var + 1e-5f);
    if (t == 0) stats[tok] = make_float2(mean, rstd);
    ushort4 ob;
    ob.x = f2bf(v.x); ob.y = f2bf(v.y); ob.z = f2bf(v.z); ob.w = f2bf(v.w);
    *reinterpret_cast<ushort4*>(&xb[(size_t)tok * H + (t << 2)]) = ob;
  }
}

// Router GEMM on MFMA (R13 verbatim, ~98us): hmid-tile = z @ (lsc*w1) via hi/lo bf16 split (3 passes).
__global__ __launch_bounds__(256) void k_router_mfma(
    const float* __restrict__ x, const float2* __restrict__ stats,
    const unsigned short* __restrict__ w1h, const unsigned short* __restrict__ w1l,
    const float* __restrict__ part, const float* __restrict__ b1, const float* __restrict__ w2,
    float* __restrict__ plog) {
  __shared__ __align__(16) short Ah[4096], Al[4096], Bh[4096], Bl[4096];
  __shared__ float2 st[128];
  int t = threadIdx.x;
  int bm = blockIdx.x << 7, bn = blockIdx.y << 7;
  if (t < 128) st[t] = stats[bm + t];
  __syncthreads();
  int arow = t >> 1, ac0 = (t & 1) << 1;
  int brow = t >> 2, bc = t & 3;
  float2 mr = st[arow];
  float rs = mr.y, mb = -mr.x * mr.y;
  const float* xsrc = &x[(size_t)(bm + arow) * H + (ac0 << 3)];
  const unsigned short* s1 = &w1h[(size_t)(bn + brow) * H + (bc << 3)];
  const unsigned short* s2 = &w1h[(size_t)(bn + brow + 64) * H + (bc << 3)];
  const unsigned short* s3 = &w1l[(size_t)(bn + brow) * H + (bc << 3)];
  const unsigned short* s4 = &w1l[(size_t)(bn + brow + 64) * H + (bc << 3)];
  float4 va0 = *(const float4*)(xsrc + 0), va1 = *(const float4*)(xsrc + 4);
  float4 va2 = *(const float4*)(xsrc + 8), va3 = *(const float4*)(xsrc + 12);
  int4 vb0 = *(const int4*)s1, vb1 = *(const int4*)s2, vb2 = *(const int4*)s3, vb3 = *(const int4*)s4;
  int lane = t & 63, wv = t >> 6;
  int wr = (wv >> 1) << 6, wc = (wv & 1) << 6;
  int l15 = lane & 15, lgp = lane >> 4;
  f32x4 acc[4][4];
#pragma unroll
  for (int i = 0; i < 4; ++i)
#pragma unroll
    for (int j = 0; j < 4; ++j) acc[i][j] = f32x4{0.f, 0.f, 0.f, 0.f};
  for (int kt = 0; kt < 32; ++kt) {
    float zz[16];
    zz[0] = fmaf(va0.x, rs, mb); zz[1] = fmaf(va0.y, rs, mb);
    zz[2] = fmaf(va0.z, rs, mb); zz[3] = fmaf(va0.w, rs, mb);
    zz[4] = fmaf(va1.x, rs, mb); zz[5] = fmaf(va1.y, rs, mb);
    zz[6] = fmaf(va1.z, rs, mb); zz[7] = fmaf(va1.w, rs, mb);
    zz[8] = fmaf(va2.x, rs, mb); zz[9] = fmaf(va2.y, rs, mb);
    zz[10] = fmaf(va2.z, rs, mb); zz[11] = fmaf(va2.w, rs, mb);
    zz[12] = fmaf(va3.x, rs, mb); zz[13] = fmaf(va3.y, rs, mb);
    zz[14] = fmaf(va3.z, rs, mb); zz[15] = fmaf(va3.w, rs, mb);
    unsigned hw[8], lw[8];
#pragma unroll
    for (int p = 0; p < 8; ++p) {
      unsigned ua = __float_as_uint(zz[2 * p]), ub = __float_as_uint(zz[2 * p + 1]);
      hw[p] = (ua >> 16) | (ub & 0xffff0000u);
      float la = zz[2 * p] - __uint_as_float(ua & 0xffff0000u);
      float lb = zz[2 * p + 1] - __uint_as_float(ub & 0xffff0000u);
      lw[p] = (__float_as_uint(la) >> 16) | (__float_as_uint(lb) & 0xffff0000u);
    }
    __syncthreads();
    *(int4*)&Ah[swz(arow, ac0)] = make_int4(hw[0], hw[1], hw[2], hw[3]);
    *(int4*)&Ah[swz(arow, ac0 + 1)] = make_int4(hw[4], hw[5], hw[6], hw[7]);
    *(int4*)&Al[swz(arow, ac0)] = make_int4(lw[0], lw[1], lw[2], lw[3]);
    *(int4*)&Al[swz(arow, ac0 + 1)] = make_int4(lw[4], lw[5], lw[6], lw[7]);
    *(int4*)&Bh[swz(brow, bc)] = vb0;
    *(int4*)&Bh[swz(brow + 64, bc)] = vb1;
    *(int4*)&Bl[swz(brow, bc)] = vb2;
    *(int4*)&Bl[swz(brow + 64, bc)] = vb3;
    __syncthreads();
    if (kt + 1 < 32) {
      xsrc += 32; s1 += 32; s2 += 32; s3 += 32; s4 += 32;
      va0 = *(const float4*)(xsrc + 0); va1 = *(const float4*)(xsrc + 4);
      va2 = *(const float4*)(xsrc + 8); va3 = *(const float4*)(xsrc + 12);
      vb0 = *(const int4*)s1; vb1 = *(const int4*)s2; vb2 = *(const int4*)s3; vb3 = *(const int4*)s4;
    }
    bf16x8 bh[4], bl[4];
#pragma unroll
    for (int j = 0; j < 4; ++j) {
      bh[j] = *(const bf16x8*)&Bh[swz(wc + (j << 4) + l15, lgp)];
      bl[j] = *(const bf16x8*)&Bl[swz(wc + (j << 4) + l15, lgp)];
    }
#pragma unroll
    for (int i = 0; i < 4; ++i) {
      bf16x8 ah = *(const bf16x8*)&Ah[swz(wr + (i << 4) + l15, lgp)];
      bf16x8 al = *(const bf16x8*)&Al[swz(wr + (i << 4) + l15, lgp)];
#pragma unroll
      for (int j = 0; j < 4; ++j) {
        acc[i][j] = __builtin_amdgcn_mfma_f32_16x16x32_bf16(ah, bh[j], acc[i][j], 0, 0, 0);
        acc[i][j] = __builtin_amdgcn_mfma_f32_16x16x32_bf16(ah, bl[j], acc[i][j], 0, 0, 0);
        acc[i][j] = __builtin_amdgcn_mfma_f32_16x16x32_bf16(al, bh[j], acc[i][j], 0, 0, 0);
      }
    }
  }
  float w2r[4][8], b1r[4];
#pragma unroll
  for (int j = 0; j < 4; ++j) {
    int col = bn + wc + (j << 4) + l15;
    float4 p0 = *(const float4*)&w2[(size_t)col * E];
    float4 p1 = *(const float4*)&w2[(size_t)col * E + 4];
    w2r[j][0] = p0.x; w2r[j][1] = p0.y; w2r[j][2] = p0.z; w2r[j][3] = p0.w;
    w2r[j][4] = p1.x; w2r[j][5] = p1.y; w2r[j][6] = p1.z; w2r[j][7] = p1.w;
    float s = b1[col];
    for (int jj = 0; jj < 32; ++jj) s += part[jj * H + col];
    b1r[j] = s;
  }
#pragma unroll
  for (int i = 0; i < 4; ++i)
#pragma unroll
    for (int j = 0; j < 4; ++j)
#pragma unroll
      for (int r = 0; r < 4; ++r) acc[i][j][r] = fmaxf(acc[i][j][r] + b1r[j], 0.f);
  int wh = wc >> 6;
  size_t pbase = ((size_t)(blockIdx.y * 2 + wh) * TT + bm) * E;
#pragma unroll
  for (int e = 0; e < E; ++e) {
    float se[4][4];
#pragma unroll
    for (int i = 0; i < 4; ++i)
#pragma unroll
      for (int r = 0; r < 4; ++r)
        se[i][r] = acc[i][0][r] * w2r[0][e] + acc[i][1][r] * w2r[1][e] +
                   acc[i][2][r] * w2r[2][e] + acc[i][3][r] * w2r[3][e];
#pragma unroll
    for (int off = 1; off < 16; off <<= 1)
#pragma unroll
      for (int i = 0; i < 4; ++i)
#pragma unroll
        for (int r = 0; r < 4; ++r) se[i][r] += __shfl_xor(se[i][r], off);
    if (l15 == 0) {
#pragma unroll
      for (int i = 0; i < 4; ++i)
#pragma unroll
        for (int r = 0; r < 4; ++r) {
          int row = wr + (i << 4) + (lgp << 2) + r;
          plog[pbase + (size_t)row * E + e] = se[i][r];
        }
    }
  }
}

// thread-per-token: sum 16 logit partials + b2 -> softmax -> top2 -> renorm; wave-aggregated lists + psum
__global__ __launch_bounds__(256) void k_top(const float* __restrict__ plog, const float* __restrict__ b2,
                                             int* __restrict__ topE, float* __restrict__ topW,
                                             int* __restrict__ listIdx, float* __restrict__ listW,
                                             int* __restrict__ cnt, double* __restrict__ psum) {
  int t = threadIdx.x, lane = t & 63;
  int tok = (blockIdx.x << 8) + t;
  float lg[E], p[E];
  float4 ba = *reinterpret_cast<const float4*>(b2);
  float4 bb = *reinterpret_cast<const float4*>(b2 + 4);
  lg[0] = ba.x; lg[1] = ba.y; lg[2] = ba.z; lg[3] = ba.w;
  lg[4] = bb.x; lg[5] = bb.y; lg[6] = bb.z; lg[7] = bb.w;
#pragma unroll
  for (int nb = 0; nb < 16; ++nb) {
    const float* pp = &plog[((size_t)nb * TT + tok) * E];
    float4 q0 = *reinterpret_cast<const float4*>(pp);
    float4 q1 = *reinterpret_cast<const float4*>(pp + 4);
    lg[0] += q0.x; lg[1] += q0.y; lg[2] += q0.z; lg[3] += q0.w;
    lg[4] += q1.x; lg[5] += q1.y; lg[6] += q1.z; lg[7] += q1.w;
  }
  float m = lg[0];
#pragma unroll
  for (int e = 1; e < E; ++e) m = fmaxf(m, lg[e]);
  float s = 0.f;
#pragma unroll
  for (int e = 0; e < E; ++e) { p[e] = __expf(lg[e] - m); s += p[e]; }
  float inv = 1.f / s;
#pragma unroll
  for (int e = 0; e < E; ++e) p[e] *= inv;
  {
    float ps[E];
#pragma unroll
    for (int e = 0; e < E; ++e) ps[e] = p[e];
#pragma unroll
    for (int off = 1; off < 64; off <<= 1)
#pragma unroll
      for (int e = 0; e < E; ++e) ps[e] += __shfl_xor(ps[e], off);
    if (lane == 0)
#pragma unroll
      for (int e = 0; e < E; ++e) atomicAdd(&psum[e], (double)ps[e]);
  }
  int e0 = 0;
#pragma unroll
  for (int e = 1; e < E; ++e) if (p[e] > p[e0]) e0 = e;  // strict >: first max (jax tie order)
  int e1 = (e0 == 0) ? 1 : 0;
#pragma unroll
  for (int e = 0; e < E; ++e) if (e != e0 && p[e] > p[e1]) e1 = e;
  float rsw = 1.f / (p[e0] + p[e1]);
  float w0 = p[e0] * rsw, w1v = p[e1] * rsw;
  topE[tok << 1] = e0; topE[(tok << 1) + 1] = e1;
  topW[tok << 1] = w0; topW[(tok << 1) + 1] = w1v;
  unsigned long long lt = (1ull << lane) - 1ull;
#pragma unroll
  for (int e = 0; e < E; ++e) {
    unsigned long long m0 = __ballot(e0 == e);
    unsigned long long m1 = __ballot(e1 == e);
    int n0 = __popcll(m0), total = n0 + __popcll(m1);
    if (total == 0) continue;  // wave-uniform
    int leader = __ffsll(m0 | m1) - 1;
    int base = 0;
    if (lane == leader) base = atomicAdd(&cnt[e], total);
    base = __shfl(base, leader);
    if (e0 == e) {
      int pos = e * TT + base + __popcll(m0 & lt);
      listIdx[pos] = (tok << 1); listW[pos] = w0;
    }
    if (e1 == e) {
      int pos = e * TT + base + n0 + __popcll(m1 & lt);
      listIdx[pos] = (tok << 1) | 1; listW[pos] = w1v;
    }
  }
}

// We cast (+ sched in block (0,0,0)): We [E][H][H] f32 -> wet [E][n][k] bf16; work list built once.
// Items are 256x256 tiles: (e, bx<ceil(cnt/256), by<4); max 128 items/expert -> slots g*8+e always fit.
#define WL_SLOTS 2048
__global__ __launch_bounds__(256) void k_cast_we(const float* __restrict__ we, unsigned short* __restrict__ wet,
                                                 const int* __restrict__ cnt, int* __restrict__ workList) {
  __shared__ unsigned short tile[32][33];
  int e = blockIdx.z;
  int kb = blockIdx.x << 5, nb = blockIdx.y << 5;
  int t = threadIdx.x;
  if (blockIdx.x == 0 && blockIdx.y == 0 && blockIdx.z == 0) {
    for (int i = t; i < WL_SLOTS; i += 256) workList[i] = -1;
    __syncthreads();
    if (t < E) {
      int ee = t;
      int nbk = (cnt[ee] + 255) >> 8;
      int g = 0;
      for (int bx = 0; bx < nbk; ++bx) {
        for (int by = 0; by < 4; ++by) {
          int item = (ee << 12) | (bx << 4) | by;
          workList[(g << 3) + ee] = item;
          ++g;
        }
      }
    }
    __syncthreads();
  }
  int cc = t & 31, rr = t >> 5;
  size_t base = (size_t)e * H * H;
#pragma unroll
  for (int r = 0; r < 4; ++r) {
    int k = kb + rr + (r << 3);
    tile[rr + (r << 3)][cc] = f2bf(we[base + (size_t)k * H + nb + cc]);
  }
  __syncthreads();
#pragma unroll
  for (int r = 0; r < 4; ++r) {
    int n = nb + rr + (r << 3);
    wet[base + (size_t)n * H + kb + cc] = tile[cc][rr + (r << 3)];
  }
}

// grouped bf16 MFMA GEMM, 256x256 tile (m248 geometry): 512 threads = 8 waves (2 row x 4 col),
// per-wave output 128x64 (acc[8][4]); BK=32. A+B gld16 2-buffer (64 KB LDS), counted vmcnt(4),
// issue-next-before-wait, 2 barriers/step, setprio around the 32-MFMA cluster.
__global__ __launch_bounds__(512) void k_expert_gemm(const unsigned short* __restrict__ xb,
                                                     const unsigned short* __restrict__ wet,
                                                     const int* __restrict__ listIdx, const float* __restrict__ listW,
                                                     const int* __restrict__ cnt, const int* __restrict__ workList,
                                                     unsigned short* __restrict__ ys) {
  int item = workList[blockIdx.x];
  if (item < 0) return;
  int e = item >> 12, bx = (item >> 4) & 255, by = item & 15;
  int c = cnt[e];
  int r0 = bx << 8, n0 = by << 8;
  __shared__ __align__(16) short A[2][8192], Bs[2][8192];  // 256 rows x 32 k each
  __shared__ int gi[256];
  __shared__ float gw[256];
  int t = threadIdx.x;
  if (t < 256) {
    int rr = r0 + t;
    gi[t] = (rr < c) ? listIdx[e * TT + rr] : -1;
    gw[t] = (rr < c) ? listW[e * TT + rr] : 0.f;
  }
  __syncthreads();
  int w = t >> 6, lane = t & 63;
  int l15 = lane & 15, lgp = lane >> 4;
  int wr = (w >> 2) << 7;   // 0 / 128
  int wc = (w & 3) << 6;    // 0 / 64 / 128 / 192
  // staging: 2 slots/thread per operand (slots t and t+512 of 1024), pre-swizzled global chunk
  int s0 = t, s1 = t + 512;
  int rA0 = s0 >> 2, cg0 = (s0 & 3) ^ ((rA0 >> 1) & 3);
  int rA1 = s1 >> 2, cg1 = (s1 & 3) ^ ((rA1 >> 1) & 3);
  int pk0 = gi[rA0], pk1 = gi[rA1];
  const unsigned short* srcA0 = xb + (size_t)((pk0 < 0) ? 0 : (pk0 >> 1)) * H + (cg0 << 3);
  const unsigned short* srcA1 = xb + (size_t)((pk1 < 0) ? 0 : (pk1 >> 1)) * H + (cg1 << 3);
  size_t wbase = (size_t)e * H * H;
  const unsigned short* srcB0 = wet + wbase + (size_t)(n0 + rA0) * H + (cg0 << 3);
  const unsigned short* srcB1 = wet + wbase + (size_t)(n0 + rA1) * H + (cg1 << 3);
  int d0 = w << 9, d1 = d0 + 4096;  // wave-uniform LDS short offsets (wave w: slots w*64.., +512)
  f32x4 acc[8][4];
#pragma unroll
  for (int i = 0; i < 8; ++i)
#pragma unroll
    for (int j = 0; j < 4; ++j) acc[i][j] = f32x4{0.f, 0.f, 0.f, 0.f};
  // prologue: stage tile 0
  gld16(&A[0][d0], srcA0); gld16(&A[0][d1], srcA1);
  gld16(&Bs[0][d0], srcB0); gld16(&Bs[0][d1], srcB1);
#pragma unroll
  for (int kt = 0; kt < 32; ++kt) {
    const int cur = kt & 1, nxt = cur ^ 1;
    if (kt < 31) {  // issue next tile first; its 4 loads stay in flight across the wait
      const int ko = (kt + 1) << 5;
      gld16(&A[nxt][d0], srcA0 + ko); gld16(&A[nxt][d1], srcA1 + ko);
      gld16(&Bs[nxt][d0], srcB0 + ko); gld16(&Bs[nxt][d1], srcB1 + ko);
      asm volatile("s_waitcnt vmcnt(4)" ::: "memory");  // tile kt landed; kt+1 in flight
    } else {
      asm volatile("s_waitcnt vmcnt(0)" ::: "memory");
    }
    __builtin_amdgcn_sched_barrier(0);
    __builtin_amdgcn_s_barrier();
    __builtin_amdgcn_sched_barrier(0);
    bf16x8 bq[4];
#pragma unroll
    for (int j = 0; j < 4; ++j) bq[j] = *(const bf16x8*)&Bs[cur][swz(wc + (j << 4) + l15, lgp)];
    __builtin_amdgcn_s_setprio(1);
#pragma unroll
    for (int i = 0; i < 8; ++i) {
      bf16x8 aq = *(const bf16x8*)&A[cur][swz(wr + (i << 4) + l15, lgp)];
#pragma unroll
      for (int j = 0; j < 4; ++j)
        acc[i][j] = __builtin_amdgcn_mfma_f32_16x16x32_bf16(aq, bq[j], acc[i][j], 0, 0, 0);
    }
    __builtin_amdgcn_s_setprio(0);
    if (kt < 31) {  // end-of-step: all waves done reading buf cur -> next step may restage it
      __builtin_amdgcn_sched_barrier(0);
      __builtin_amdgcn_s_barrier();
    }
  }
#pragma unroll
  for (int i = 0; i < 8; ++i) {
#pragma unroll
    for (int r = 0; r < 4; ++r) {
      int row = wr + (i << 4) + (lgp << 2) + r;  // C/D: col=lane&15, row=(lane>>4)*4+reg
      int pk = gi[row];
      if (pk < 0) continue;
      int tok = pk >> 1, slot = pk & 1;
      float wgt = gw[row];
      size_t ob = ((size_t)slot * TT + tok) * H + n0 + wc + l15;
#pragma unroll
      for (int j = 0; j < 4; ++j) ys[ob + (j << 4)] = __half_as_ushort(__float2half(wgt * acc[i][j][r]));
    }
  }
}

// out = y_slot0 + y_slot1 + w0*be[e0] + w1*be[e1]; block 0 thread 0 also computes aux.
__global__ __launch_bounds__(256) void k_combine(const unsigned short* __restrict__ ys, const int* __restrict__ topE,
                                                 const float* __restrict__ topW, const float* __restrict__ be,
                                                 const double* __restrict__ psum, float* __restrict__ out) {
  int tok = blockIdx.x, t = threadIdx.x;
  if (tok == 0 && t == 0) {
    double a = 0.0;
    for (int e = 0; e < E; ++e) {
      double mp = psum[e] / (double)TT;
      a += mp * log(mp * (double)E + 1e-9);
    }
    out[(size_t)TT * H] = (float)a;
  }
  int e0 = topE[tok << 1], e1 = topE[(tok << 1) + 1];
  float w0 = topW[tok << 1], w1v = topW[(tok << 1) + 1];
  int h = t << 2;
  size_t base = (size_t)tok * H + h;
  ushort4 a = *reinterpret_cast<const ushort4*>(&ys[base]);
  ushort4 b = *reinterpret_cast<const ushort4*>(&ys[(size_t)TT * H + base]);
  float4 b0 = *reinterpret_cast<const float4*>(&be[e0 * H + h]);
  float4 b1v = *reinterpret_cast<const float4*>(&be[e1 * H + h]);
  float4 o;
  o.x = __half2float(__ushort_as_half(a.x)) + __half2float(__ushort_as_half(b.x)) + w0 * b0.x + w1v * b1v.x;
  o.y = __half2float(__ushort_as_half(a.y)) + __half2float(__ushort_as_half(b.y)) + w0 * b0.y + w1v * b1v.y;
  o.z = __half2float(__ushort_as_half(a.z)) + __half2float(__ushort_as_half(b.z)) + w0 * b0.z + w1v * b1v.z;
  o.w = __half2float(__ushort_as_half(a.w)) + __half2float(__ushort_as_half(b.w)) + w0 * b0.w + w1v * b1v.w;
  *reinterpret_cast<float4*>(&out[base]) = o;
}

extern "C" void kernel_launch(void* const* d_in, const int* in_sizes, int n_in, void* d_out, int out_size, void* d_ws,
                              size_t ws_size, hipStream_t stream) {
  const float* x = (const float*)d_in[0];
  const float* lsc = (const float*)d_in[1];
  const float* lbi = (const float*)d_in[2];
  const float* w1 = (const float*)d_in[3];
  const float* b1 = (const float*)d_in[4];
  const float* w2 = (const float*)d_in[5];
  const float* b2 = (const float*)d_in[6];
  const float* we = (const float*)d_in[7];
  const float* be = (const float*)d_in[8];
  float* out = (float*)d_out;
  char* ws = (char*)d_ws;

  // ws timeline (peak 66 MB):
  // [0,2M): small; [2,18M): xb bf16; [18,34M): wet bf16;
  // [34,38M): w1h+w1l (dead after router); [38,54M): plog (dead after k_top);
  // ys fp16 [2][TT][H] = [34,66M) (born at expert; overlays w1h/plog).
  char* p = ws;
  int* topE = (int*)p; p += TT * 2 * 4;
  float* topW = (float*)p; p += TT * 2 * 4;
  int* listIdx = (int*)p; p += E * TT * 4;
  float* listW = (float*)p; p += E * TT * 4;
  int* cnt = (int*)p; p += 256;
  double* psum = (double*)p; p += 2048;
  float* part = (float*)p; p += 32 * H * 4;
  int* workList = (int*)p; p += WL_SLOTS * 4;
  float2* stats = (float2*)p; p += TT * 8;
  unsigned short* xb = (unsigned short*)(ws + (2ull << 20));
  unsigned short* wet = (unsigned short*)(ws + (18ull << 20));
  unsigned short* w1h = (unsigned short*)(ws + (34ull << 20));
  unsigned short* w1l = (unsigned short*)(ws + (36ull << 20));
  float* plog = (float*)(ws + (38ull << 20));
  unsigned short* ys = (unsigned short*)(ws + (34ull << 20));  // overlays w1h/w1l/plog (after k_top)

  k_pre<<<1024 + TT, 256, 0, stream>>>(w1, lsc, lbi, x, w1h, w1l, part, stats, xb, cnt, psum);
  k_router_mfma<<<dim3(TT / 128, H / 128), 256, 0, stream>>>(x, stats, w1h, w1l, part, b1, w2, plog);
  k_top<<<TT / 256, 256, 0, stream>>>(plog, b2, topE, topW, listIdx, listW, cnt, psum);
  k_cast_we<<<dim3(32, 32, E), 256, 0, stream>>>(we, wet, cnt, workList);
  k_expert_gemm<<<WL_SLOTS, 512, 0, stream>>>(xb, wet, listIdx, listW, cnt, workList, ys);
  k_combine<<<TT, 256, 0, stream>>>(ys, topE, topW, be, psum, out);
}

// Round 16
// 203.897 us; speedup vs baseline: 1.0644x; 1.0644x over previous
//
#include <hip/hip_runtime.h>
#include <hip/hip_fp16.h>

#define H 1024
#define E 8
#define TT 8192  // tokens = B*S

typedef __attribute__((ext_vector_type(8))) short bf16x8;
typedef __attribute__((ext_vector_type(4))) float f32x4;

__device__ __forceinline__ unsigned short f2bf(float f) {
  unsigned int u = __float_as_uint(f);
  u += 0x7fffu + ((u >> 16) & 1u);
  return (unsigned short)(u >> 16);
}

// LDS tile addressing: rows of 32 bf16 = 64B = 4 chunks of 16B.
// XOR swizzle chunk' = c ^ ((row>>1)&3): conflict-free writes AND mfma b128 reads (0 conflicts, R3-R15).
__device__ __forceinline__ int swz(int row, int c) {
  return (row << 5) | (((c ^ (row >> 1)) & 3) << 3);
}

// async global->LDS, 16B per lane; LDS dest = wave-uniform base + lane*16 (linear).
__device__ __forceinline__ void gld16(void* lds, const void* g) {
  __builtin_amdgcn_global_load_lds((const __attribute__((address_space(1))) void*)g,
                                   (__attribute__((address_space(3))) void*)lds, 16, 0, 0);
}

// Fused roots: blocks [0,1024) = cast_w1 (+part partials, +init cnt/psum); blocks [1024,9216) = stats.
__global__ __launch_bounds__(256) void k_pre(const float* __restrict__ w1, const float* __restrict__ lsc,
                                             const float* __restrict__ lbi, const float* __restrict__ x,
                                             unsigned short* __restrict__ w1h, unsigned short* __restrict__ w1l,
                                             float* __restrict__ part, float2* __restrict__ stats,
                                             unsigned short* __restrict__ xb, int* __restrict__ cnt,
                                             double* __restrict__ psum) {
  int blk = blockIdx.x;
  int t = threadIdx.x;
  if (blk < 1024) {
    // ---- cast_w1 ----
    __shared__ float tile[32][33];
    __shared__ float red[8][33];
    int kb = (blk & 31) << 5, nb = (blk >> 5) << 5;
    int cc = t & 31, rr = t >> 5;
    if (blk == 0 && t < E) { cnt[t] = 0; psum[t] = 0.0; }
#pragma unroll
    for (int r = 0; r < 4; ++r) {
      int k = kb + rr + (r << 3);
      tile[rr + (r << 3)][cc] = w1[(size_t)k * H + nb + cc];
    }
    __syncthreads();
    float pp = 0.f;
#pragma unroll
    for (int r = 0; r < 4; ++r) {
      int kk = rr + (r << 3);
      pp = fmaf(lbi[kb + kk], tile[kk][cc], pp);
    }
    red[rr][cc] = pp;
    float scale = lsc[kb + cc];
    __syncthreads();
    if (rr == 0) {
      float s = 0.f;
#pragma unroll
      for (int j = 0; j < 8; ++j) s += red[j][cc];
      part[(blk & 31) * H + nb + cc] = s;
    }
#pragma unroll
    for (int r = 0; r < 4; ++r) {
      int n = nb + rr + (r << 3);
      float v = tile[cc][rr + (r << 3)] * scale;
      unsigned short h = f2bf(v);
      float hv = __uint_as_float((unsigned)h << 16);
      unsigned short l = f2bf(v - hv);
      w1h[(size_t)n * H + kb + cc] = h;
      w1l[(size_t)n * H + kb + cc] = l;
    }
  } else {
    // ---- stats ----
    int tok = blk - 1024;
    const float4 v = *reinterpret_cast<const float4*>(&x[(size_t)tok * H + (t << 2)]);
    float s = v.x + v.y + v.z + v.w;
    float ss = v.x * v.x + v.y * v.y + v.z * v.z + v.w * v.w;
#pragma unroll
    for (int off = 32; off; off >>= 1) { s += __shfl_down(s, off); ss += __shfl_down(ss, off); }
    __shared__ float red2[4][2];
    int lane = t & 63, wv = t >> 6;
    if (lane == 0) { red2[wv][0] = s; red2[wv][1] = ss; }
    __syncthreads();
    float fs = red2[0][0] + red2[1][0] + red2[2][0] + red2[3][0];
    float fss = red2[0][1] + red2[1][1] + red2[2][1] + red2[3][1];
    float mean = fs * (1.0f / H);
    float var = fss * (1.0f / H) - mean * mean;
    float rstd = rsqrtf(var + 1e-5f);
    if (t == 0) stats[tok] = make_float2(mean, rstd);
    ushort4 ob;
    ob.x = f2bf(v.x); ob.y = f2bf(v.y); ob.z = f2bf(v.z); ob.w = f2bf(v.w);
    *reinterpret_cast<ushort4*>(&xb[(size_t)tok * H + (t << 2)]) = ob;
  }
}

// Router GEMM on MFMA: hmid-tile = z @ (lsc*w1) via hi/lo bf16 split (3 passes), z=(x-m)*rstd.
// 128x128 tile, BK=32, 4 waves 2x2, swizzled LDS, register prefetch, 33 KB LDS -> 4 blocks/CU.
// Epilogue computes its own b1eff slice, then relu(tile+b1eff) @ w2 partials -> plog.
__global__ __launch_bounds__(256) void k_router_mfma(
    const float* __restrict__ x, const float2* __restrict__ stats,
    const unsigned short* __restrict__ w1h, const unsigned short* __restrict__ w1l,
    const float* __restrict__ part, const float* __restrict__ b1, const float* __restrict__ w2,
    float* __restrict__ plog) {
  __shared__ __align__(16) short Ah[4096], Al[4096], Bh[4096], Bl[4096];
  __shared__ float2 st[128];
  int t = threadIdx.x;
  int bm = blockIdx.x << 7, bn = blockIdx.y << 7;
  if (t < 128) st[t] = stats[bm + t];
  __syncthreads();
  int arow = t >> 1, ac0 = (t & 1) << 1;
  int brow = t >> 2, bc = t & 3;
  float2 mr = st[arow];
  float rs = mr.y, mb = -mr.x * mr.y;
  const float* xsrc = &x[(size_t)(bm + arow) * H + (ac0 << 3)];
  const unsigned short* s1 = &w1h[(size_t)(bn + brow) * H + (bc << 3)];
  const unsigned short* s2 = &w1h[(size_t)(bn + brow + 64) * H + (bc << 3)];
  const unsigned short* s3 = &w1l[(size_t)(bn + brow) * H + (bc << 3)];
  const unsigned short* s4 = &w1l[(size_t)(bn + brow + 64) * H + (bc << 3)];
  float4 va0 = *(const float4*)(xsrc + 0), va1 = *(const float4*)(xsrc + 4);
  float4 va2 = *(const float4*)(xsrc + 8), va3 = *(const float4*)(xsrc + 12);
  int4 vb0 = *(const int4*)s1, vb1 = *(const int4*)s2, vb2 = *(const int4*)s3, vb3 = *(const int4*)s4;
  int lane = t & 63, wv = t >> 6;
  int wr = (wv >> 1) << 6, wc = (wv & 1) << 6;
  int l15 = lane & 15, lgp = lane >> 4;
  f32x4 acc[4][4];
#pragma unroll
  for (int i = 0; i < 4; ++i)
#pragma unroll
    for (int j = 0; j < 4; ++j) acc[i][j] = f32x4{0.f, 0.f, 0.f, 0.f};
  for (int kt = 0; kt < 32; ++kt) {
    float zz[16];
    zz[0] = fmaf(va0.x, rs, mb); zz[1] = fmaf(va0.y, rs, mb);
    zz[2] = fmaf(va0.z, rs, mb); zz[3] = fmaf(va0.w, rs, mb);
    zz[4] = fmaf(va1.x, rs, mb); zz[5] = fmaf(va1.y, rs, mb);
    zz[6] = fmaf(va1.z, rs, mb); zz[7] = fmaf(va1.w, rs, mb);
    zz[8] = fmaf(va2.x, rs, mb); zz[9] = fmaf(va2.y, rs, mb);
    zz[10] = fmaf(va2.z, rs, mb); zz[11] = fmaf(va2.w, rs, mb);
    zz[12] = fmaf(va3.x, rs, mb); zz[13] = fmaf(va3.y, rs, mb);
    zz[14] = fmaf(va3.z, rs, mb); zz[15] = fmaf(va3.w, rs, mb);
    unsigned hw[8], lw[8];
#pragma unroll
    for (int p = 0; p < 8; ++p) {
      unsigned ua = __float_as_uint(zz[2 * p]), ub = __float_as_uint(zz[2 * p + 1]);
      hw[p] = (ua >> 16) | (ub & 0xffff0000u);
      float la = zz[2 * p] - __uint_as_float(ua & 0xffff0000u);
      float lb = zz[2 * p + 1] - __uint_as_float(ub & 0xffff0000u);
      lw[p] = (__float_as_uint(la) >> 16) | (__float_as_uint(lb) & 0xffff0000u);
    }
    __syncthreads();
    *(int4*)&Ah[swz(arow, ac0)] = make_int4(hw[0], hw[1], hw[2], hw[3]);
    *(int4*)&Ah[swz(arow, ac0 + 1)] = make_int4(hw[4], hw[5], hw[6], hw[7]);
    *(int4*)&Al[swz(arow, ac0)] = make_int4(lw[0], lw[1], lw[2], lw[3]);
    *(int4*)&Al[swz(arow, ac0 + 1)] = make_int4(lw[4], lw[5], lw[6], lw[7]);
    *(int4*)&Bh[swz(brow, bc)] = vb0;
    *(int4*)&Bh[swz(brow + 64, bc)] = vb1;
    *(int4*)&Bl[swz(brow, bc)] = vb2;
    *(int4*)&Bl[swz(brow + 64, bc)] = vb3;
    __syncthreads();
    if (kt + 1 < 32) {
      xsrc += 32; s1 += 32; s2 += 32; s3 += 32; s4 += 32;
      va0 = *(const float4*)(xsrc + 0); va1 = *(const float4*)(xsrc + 4);
      va2 = *(const float4*)(xsrc + 8); va3 = *(const float4*)(xsrc + 12);
      vb0 = *(const int4*)s1; vb1 = *(const int4*)s2; vb2 = *(const int4*)s3; vb3 = *(const int4*)s4;
    }
    bf16x8 bh[4], bl[4];
#pragma unroll
    for (int j = 0; j < 4; ++j) {
      bh[j] = *(const bf16x8*)&Bh[swz(wc + (j << 4) + l15, lgp)];
      bl[j] = *(const bf16x8*)&Bl[swz(wc + (j << 4) + l15, lgp)];
    }
#pragma unroll
    for (int i = 0; i < 4; ++i) {
      bf16x8 ah = *(const bf16x8*)&Ah[swz(wr + (i << 4) + l15, lgp)];
      bf16x8 al = *(const bf16x8*)&Al[swz(wr + (i << 4) + l15, lgp)];
#pragma unroll
      for (int j = 0; j < 4; ++j) {
        acc[i][j] = __builtin_amdgcn_mfma_f32_16x16x32_bf16(ah, bh[j], acc[i][j], 0, 0, 0);
        acc[i][j] = __builtin_amdgcn_mfma_f32_16x16x32_bf16(ah, bl[j], acc[i][j], 0, 0, 0);
        acc[i][j] = __builtin_amdgcn_mfma_f32_16x16x32_bf16(al, bh[j], acc[i][j], 0, 0, 0);
      }
    }
  }
  // epilogue: per-block b1eff slice (bit-identical order to old k_b1b), bias + relu, logits partials
  float w2r[4][8], b1r[4];
#pragma unroll
  for (int j = 0; j < 4; ++j) {
    int col = bn + wc + (j << 4) + l15;
    float4 p0 = *(const float4*)&w2[(size_t)col * E];
    float4 p1 = *(const float4*)&w2[(size_t)col * E + 4];
    w2r[j][0] = p0.x; w2r[j][1] = p0.y; w2r[j][2] = p0.z; w2r[j][3] = p0.w;
    w2r[j][4] = p1.x; w2r[j][5] = p1.y; w2r[j][6] = p1.z; w2r[j][7] = p1.w;
    float s = b1[col];
    for (int jj = 0; jj < 32; ++jj) s += part[jj * H + col];
    b1r[j] = s;
  }
#pragma unroll
  for (int i = 0; i < 4; ++i)
#pragma unroll
    for (int j = 0; j < 4; ++j)
#pragma unroll
      for (int r = 0; r < 4; ++r) acc[i][j][r] = fmaxf(acc[i][j][r] + b1r[j], 0.f);
  int wh = wc >> 6;
  size_t pbase = ((size_t)(blockIdx.y * 2 + wh) * TT + bm) * E;
#pragma unroll
  for (int e = 0; e < E; ++e) {
    float se[4][4];
#pragma unroll
    for (int i = 0; i < 4; ++i)
#pragma unroll
      for (int r = 0; r < 4; ++r)
        se[i][r] = acc[i][0][r] * w2r[0][e] + acc[i][1][r] * w2r[1][e] +
                   acc[i][2][r] * w2r[2][e] + acc[i][3][r] * w2r[3][e];
#pragma unroll
    for (int off = 1; off < 16; off <<= 1)
#pragma unroll
      for (int i = 0; i < 4; ++i)
#pragma unroll
        for (int r = 0; r < 4; ++r) se[i][r] += __shfl_xor(se[i][r], off);
    if (l15 == 0) {
#pragma unroll
      for (int i = 0; i < 4; ++i)
#pragma unroll
        for (int r = 0; r < 4; ++r) {
          int row = wr + (i << 4) + (lgp << 2) + r;
          plog[pbase + (size_t)row * E + e] = se[i][r];
        }
    }
  }
}

// thread-per-token: sum 16 logit partials + b2 -> softmax -> top2 -> renorm; wave-aggregated lists + psum
__global__ __launch_bounds__(256) void k_top(const float* __restrict__ plog, const float* __restrict__ b2,
                                             int* __restrict__ topE, float* __restrict__ topW,
                                             int* __restrict__ listIdx, float* __restrict__ listW,
                                             int* __restrict__ cnt, double* __restrict__ psum) {
  int t = threadIdx.x, lane = t & 63;
  int tok = (blockIdx.x << 8) + t;
  float lg[E], p[E];
  float4 ba = *reinterpret_cast<const float4*>(b2);
  float4 bb = *reinterpret_cast<const float4*>(b2 + 4);
  lg[0] = ba.x; lg[1] = ba.y; lg[2] = ba.z; lg[3] = ba.w;
  lg[4] = bb.x; lg[5] = bb.y; lg[6] = bb.z; lg[7] = bb.w;
#pragma unroll
  for (int nb = 0; nb < 16; ++nb) {
    const float* pp = &plog[((size_t)nb * TT + tok) * E];
    float4 q0 = *reinterpret_cast<const float4*>(pp);
    float4 q1 = *reinterpret_cast<const float4*>(pp + 4);
    lg[0] += q0.x; lg[1] += q0.y; lg[2] += q0.z; lg[3] += q0.w;
    lg[4] += q1.x; lg[5] += q1.y; lg[6] += q1.z; lg[7] += q1.w;
  }
  float m = lg[0];
#pragma unroll
  for (int e = 1; e < E; ++e) m = fmaxf(m, lg[e]);
  float s = 0.f;
#pragma unroll
  for (int e = 0; e < E; ++e) { p[e] = __expf(lg[e] - m); s += p[e]; }
  float inv = 1.f / s;
#pragma unroll
  for (int e = 0; e < E; ++e) p[e] *= inv;
  {
    float ps[E];
#pragma unroll
    for (int e = 0; e < E; ++e) ps[e] = p[e];
#pragma unroll
    for (int off = 1; off < 64; off <<= 1)
#pragma unroll
      for (int e = 0; e < E; ++e) ps[e] += __shfl_xor(ps[e], off);
    if (lane == 0)
#pragma unroll
      for (int e = 0; e < E; ++e) atomicAdd(&psum[e], (double)ps[e]);
  }
  int e0 = 0;
#pragma unroll
  for (int e = 1; e < E; ++e) if (p[e] > p[e0]) e0 = e;  // strict >: first max (jax tie order)
  int e1 = (e0 == 0) ? 1 : 0;
#pragma unroll
  for (int e = 0; e < E; ++e) if (e != e0 && p[e] > p[e1]) e1 = e;
  float rsw = 1.f / (p[e0] + p[e1]);
  float w0 = p[e0] * rsw, w1v = p[e1] * rsw;
  topE[tok << 1] = e0; topE[(tok << 1) + 1] = e1;
  topW[tok << 1] = w0; topW[(tok << 1) + 1] = w1v;
  unsigned long long lt = (1ull << lane) - 1ull;
#pragma unroll
  for (int e = 0; e < E; ++e) {
    unsigned long long m0 = __ballot(e0 == e);
    unsigned long long m1 = __ballot(e1 == e);
    int n0 = __popcll(m0), total = n0 + __popcll(m1);
    if (total == 0) continue;  // wave-uniform
    int leader = __ffsll(m0 | m1) - 1;
    int base = 0;
    if (lane == leader) base = atomicAdd(&cnt[e], total);
    base = __shfl(base, leader);
    if (e0 == e) {
      int pos = e * TT + base + __popcll(m0 & lt);
      listIdx[pos] = (tok << 1); listW[pos] = w0;
    }
    if (e1 == e) {
      int pos = e * TT + base + n0 + __popcll(m1 & lt);
      listIdx[pos] = (tok << 1) | 1; listW[pos] = w1v;
    }
  }
}

// We cast (+ sched in block (0,0,0)): We [E][H][H] f32 -> wet [E][n][k] bf16; work list built once.
#define WL_SLOTS 2560
__global__ __launch_bounds__(256) void k_cast_we(const float* __restrict__ we, unsigned short* __restrict__ wet,
                                                 const int* __restrict__ cnt, int* __restrict__ workList) {
  __shared__ unsigned short tile[32][33];
  int e = blockIdx.z;
  int kb = blockIdx.x << 5, nb = blockIdx.y << 5;
  int t = threadIdx.x;
  if (blockIdx.x == 0 && blockIdx.y == 0 && blockIdx.z == 0) {
    // sched: runs after k_top (cnt final). item (e,bx,by) at slot g*8+e; overflow region per expert.
    for (int i = t; i < WL_SLOTS; i += 256) workList[i] = -1;
    __syncthreads();
    if (t < E) {
      int ee = t;
      int nbk = (cnt[ee] + 127) >> 7;
      int ov = 2048 + (ee << 6);
      int g = 0;
      for (int bx = 0; bx < nbk; ++bx) {
        for (int by = 0; by < 8; ++by) {
          int item = (ee << 12) | (bx << 4) | by;
          int slot = (g < 256) ? ((g << 3) + ee) : ov++;
          workList[slot] = item;
          ++g;
        }
      }
    }
    __syncthreads();
  }
  int cc = t & 31, rr = t >> 5;
  size_t base = (size_t)e * H * H;
#pragma unroll
  for (int r = 0; r < 4; ++r) {
    int k = kb + rr + (r << 3);
    tile[rr + (r << 3)][cc] = f2bf(we[base + (size_t)k * H + nb + cc]);
  }
  __syncthreads();
#pragma unroll
  for (int r = 0; r < 4; ++r) {
    int n = nb + rr + (r << 3);
    wet[base + (size_t)n * H + kb + cc] = tile[cc][rr + (r << 3)];
  }
}

// grouped bf16 MFMA GEMM via exact work list (measured 97us):
// BM=128, BN=128, BK=32; 4 waves 2x2; A+B gld16 2-buffer (33 KB -> 4 blocks/CU); counted vmcnt(4);
// 2 barriers/step; setprio around MFMA cluster.
__global__ __launch_bounds__(256) void k_expert_gemm(const unsigned short* __restrict__ xb,
                                                     const unsigned short* __restrict__ wet,
                                                     const int* __restrict__ listIdx, const float* __restrict__ listW,
                                                     const int* __restrict__ cnt, const int* __restrict__ workList,
                                                     unsigned short* __restrict__ ys) {
  int item = workList[blockIdx.x];
  if (item < 0) return;
  int e = item >> 12, bx = (item >> 4) & 255, by = item & 15;
  int c = cnt[e];
  int r0 = bx << 7, n0 = by << 7;
  __shared__ __align__(16) short A[2][4096], Bs[2][4096];
  __shared__ int gi[128];
  __shared__ float gw[128];
  int t = threadIdx.x;
  if (t < 128) {
    int rr = r0 + t;
    gi[t] = (rr < c) ? listIdx[e * TT + rr] : -1;
    gw[t] = (rr < c) ? listW[e * TT + rr] : 0.f;
  }
  __syncthreads();
  int w = t >> 6, lane = t & 63;
  int l15 = lane & 15, lgp = lane >> 4;
  int wr = (w >> 1) << 6, wc = (w & 1) << 6;
  // staging: 2 slots/thread per operand, pre-swizzled global chunk
  int s0 = (w << 7) + lane, s1 = s0 + 64;
  int rA0 = s0 >> 2, cg0 = (s0 & 3) ^ ((rA0 >> 1) & 3);
  int rA1 = s1 >> 2, cg1 = (s1 & 3) ^ ((rA1 >> 1) & 3);
  int pk0 = gi[rA0], pk1 = gi[rA1];
  const unsigned short* srcA0 = xb + (size_t)((pk0 < 0) ? 0 : (pk0 >> 1)) * H + (cg0 << 3);
  const unsigned short* srcA1 = xb + (size_t)((pk1 < 0) ? 0 : (pk1 >> 1)) * H + (cg1 << 3);
  size_t wbase = (size_t)e * H * H;
  const unsigned short* srcB0 = wet + wbase + (size_t)(n0 + rA0) * H + (cg0 << 3);
  const unsigned short* srcB1 = wet + wbase + (size_t)(n0 + rA1) * H + (cg1 << 3);
  int d0 = (w << 10), d1 = d0 + 512;  // wave-uniform LDS short offsets
  f32x4 acc[4][4];
#pragma unroll
  for (int i = 0; i < 4; ++i)
#pragma unroll
    for (int j = 0; j < 4; ++j) acc[i][j] = f32x4{0.f, 0.f, 0.f, 0.f};
  // prologue: stage tile 0
  gld16(&A[0][d0], srcA0); gld16(&A[0][d1], srcA1);
  gld16(&Bs[0][d0], srcB0); gld16(&Bs[0][d1], srcB1);
#pragma unroll
  for (int kt = 0; kt < 32; ++kt) {
    const int cur = kt & 1, nxt = cur ^ 1;
    if (kt < 31) {  // issue next tile first; its 4 loads stay in flight across the wait
      const int ko = (kt + 1) << 5;
      gld16(&A[nxt][d0], srcA0 + ko); gld16(&A[nxt][d1], srcA1 + ko);
      gld16(&Bs[nxt][d0], srcB0 + ko); gld16(&Bs[nxt][d1], srcB1 + ko);
      asm volatile("s_waitcnt vmcnt(4)" ::: "memory");  // tile kt landed; kt+1 in flight
    } else {
      asm volatile("s_waitcnt vmcnt(0)" ::: "memory");
    }
    __builtin_amdgcn_sched_barrier(0);
    __builtin_amdgcn_s_barrier();
    __builtin_amdgcn_sched_barrier(0);
    bf16x8 bq[4];
#pragma unroll
    for (int j = 0; j < 4; ++j) bq[j] = *(const bf16x8*)&Bs[cur][swz(wc + (j << 4) + l15, lgp)];
    bf16x8 aq[4];
#pragma unroll
    for (int i = 0; i < 4; ++i) aq[i] = *(const bf16x8*)&A[cur][swz(wr + (i << 4) + l15, lgp)];
    __builtin_amdgcn_s_setprio(1);
#pragma unroll
    for (int i = 0; i < 4; ++i)
#pragma unroll
      for (int j = 0; j < 4; ++j)
        acc[i][j] = __builtin_amdgcn_mfma_f32_16x16x32_bf16(aq[i], bq[j], acc[i][j], 0, 0, 0);
    __builtin_amdgcn_s_setprio(0);
    if (kt < 31) {  // end-of-step: all waves done reading buf cur -> next step may restage it
      __builtin_amdgcn_sched_barrier(0);
      __builtin_amdgcn_s_barrier();
    }
  }
#pragma unroll
  for (int i = 0; i < 4; ++i) {
#pragma unroll
    for (int r = 0; r < 4; ++r) {
      int row = wr + (i << 4) + (lgp << 2) + r;  // C/D: col=lane&15, row=(lane>>4)*4+reg
      int pk = gi[row];
      if (pk < 0) continue;
      int tok = pk >> 1, slot = pk & 1;
      float wgt = gw[row];
      size_t ob = ((size_t)slot * TT + tok) * H + n0 + wc + l15;
#pragma unroll
      for (int j = 0; j < 4; ++j) ys[ob + (j << 4)] = __half_as_ushort(__float2half(wgt * acc[i][j][r]));
    }
  }
}

// out = y_slot0 + y_slot1 + w0*be[e0] + w1*be[e1]; block 0 thread 0 also computes aux.
__global__ __launch_bounds__(256) void k_combine(const unsigned short* __restrict__ ys, const int* __restrict__ topE,
                                                 const float* __restrict__ topW, const float* __restrict__ be,
                                                 const double* __restrict__ psum, float* __restrict__ out) {
  int tok = blockIdx.x, t = threadIdx.x;
  if (tok == 0 && t == 0) {
    double a = 0.0;
    for (int e = 0; e < E; ++e) {
      double mp = psum[e] / (double)TT;
      a += mp * log(mp * (double)E + 1e-9);
    }
    out[(size_t)TT * H] = (float)a;
  }
  int e0 = topE[tok << 1], e1 = topE[(tok << 1) + 1];
  float w0 = topW[tok << 1], w1v = topW[(tok << 1) + 1];
  int h = t << 2;
  size_t base = (size_t)tok * H + h;
  ushort4 a = *reinterpret_cast<const ushort4*>(&ys[base]);
  ushort4 b = *reinterpret_cast<const ushort4*>(&ys[(size_t)TT * H + base]);
  float4 b0 = *reinterpret_cast<const float4*>(&be[e0 * H + h]);
  float4 b1v = *reinterpret_cast<const float4*>(&be[e1 * H + h]);
  float4 o;
  o.x = __half2float(__ushort_as_half(a.x)) + __half2float(__ushort_as_half(b.x)) + w0 * b0.x + w1v * b1v.x;
  o.y = __half2float(__ushort_as_half(a.y)) + __half2float(__ushort_as_half(b.y)) + w0 * b0.y + w1v * b1v.y;
  o.z = __half2float(__ushort_as_half(a.z)) + __half2float(__ushort_as_half(b.z)) + w0 * b0.z + w1v * b1v.z;
  o.w = __half2float(__ushort_as_half(a.w)) + __half2float(__ushort_as_half(b.w)) + w0 * b0.w + w1v * b1v.w;
  *reinterpret_cast<float4*>(&out[base]) = o;
}

extern "C" void kernel_launch(void* const* d_in, const int* in_sizes, int n_in, void* d_out, int out_size, void* d_ws,
                              size_t ws_size, hipStream_t stream) {
  const float* x = (const float*)d_in[0];
  const float* lsc = (const float*)d_in[1];
  const float* lbi = (const float*)d_in[2];
  const float* w1 = (const float*)d_in[3];
  const float* b1 = (const float*)d_in[4];
  const float* w2 = (const float*)d_in[5];
  const float* b2 = (const float*)d_in[6];
  const float* we = (const float*)d_in[7];
  const float* be = (const float*)d_in[8];
  float* out = (float*)d_out;
  char* ws = (char*)d_ws;

  // ws timeline (peak 66 MB):
  // [0,2M): small; [2,18M): xb bf16; [18,34M): wet bf16;
  // [34,38M): w1h+w1l (dead after router); [38,54M): plog (dead after k_top);
  // ys fp16 [2][TT][H] = [34,66M) (born at expert; overlays w1h/plog).
  char* p = ws;
  int* topE = (int*)p; p += TT * 2 * 4;
  float* topW = (float*)p; p += TT * 2 * 4;
  int* listIdx = (int*)p; p += E * TT * 4;
  float* listW = (float*)p; p += E * TT * 4;
  int* cnt = (int*)p; p += 256;
  double* psum = (double*)p; p += 2048;
  float* part = (float*)p; p += 32 * H * 4;
  int* workList = (int*)p; p += WL_SLOTS * 4;
  float2* stats = (float2*)p; p += TT * 8;
  unsigned short* xb = (unsigned short*)(ws + (2ull << 20));
  unsigned short* wet = (unsigned short*)(ws + (18ull << 20));
  unsigned short* w1h = (unsigned short*)(ws + (34ull << 20));
  unsigned short* w1l = (unsigned short*)(ws + (36ull << 20));
  float* plog = (float*)(ws + (38ull << 20));
  unsigned short* ys = (unsigned short*)(ws + (34ull << 20));  // overlays w1h/w1l/plog (after k_top)

  k_pre<<<1024 + TT, 256, 0, stream>>>(w1, lsc, lbi, x, w1h, w1l, part, stats, xb, cnt, psum);
  k_router_mfma<<<dim3(TT / 128, H / 128), 256, 0, stream>>>(x, stats, w1h, w1l, part, b1, w2, plog);
  k_top<<<TT / 256, 256, 0, stream>>>(plog, b2, topE, topW, listIdx, listW, cnt, psum);
  k_cast_we<<<dim3(32, 32, E), 256, 0, stream>>>(we, wet, cnt, workList);
  k_expert_gemm<<<WL_SLOTS, 256, 0, stream>>>(xb, wet, listIdx, listW, cnt, workList, ys);
  k_combine<<<TT, 256, 0, stream>>>(ys, topE, topW, be, psum, out);
}

// Round 18
// 202.691 us; speedup vs baseline: 1.0707x; 1.0060x over previous
//
#include <hip/hip_runtime.h>
#include <hip/hip_fp16.h>

#define H 1024
#define E 8
#define TT 8192  // tokens = B*S

typedef __attribute__((ext_vector_type(8))) short bf16x8;
typedef __attribute__((ext_vector_type(4))) float f32x4;

__device__ __forceinline__ unsigned short f2bf(float f) {
  unsigned int u = __float_as_uint(f);
  u += 0x7fffu + ((u >> 16) & 1u);
  return (unsigned short)(u >> 16);
}

// LDS tile addressing: rows of 32 bf16 = 64B = 4 chunks of 16B.
// XOR swizzle chunk' = c ^ ((row>>1)&3): conflict-free writes AND mfma b128 reads (0 conflicts, R3-R16).
__device__ __forceinline__ int swz(int row, int c) {
  return (row << 5) | (((c ^ (row >> 1)) & 3) << 3);
}

// async global->LDS, 16B per lane; LDS dest = wave-uniform base + lane*16 (linear).
__device__ __forceinline__ void gld16(void* lds, const void* g) {
  __builtin_amdgcn_global_load_lds((const __attribute__((address_space(1))) void*)g,
                                   (__attribute__((address_space(3))) void*)lds, 16, 0, 0);
}

// Fused roots: blocks [0,1024) = cast_w1 (+part partials, +init cnt/psum);
// blocks [1024,9216) = stats -> xb (rounded bf16 of raw x) AND zh/zl (trunc hi/lo split of LN(x)).
__global__ __launch_bounds__(256) void k_pre(const float* __restrict__ w1, const float* __restrict__ lsc,
                                             const float* __restrict__ lbi, const float* __restrict__ x,
                                             unsigned short* __restrict__ w1h, unsigned short* __restrict__ w1l,
                                             float* __restrict__ part, unsigned short* __restrict__ xb,
                                             unsigned short* __restrict__ zh, unsigned short* __restrict__ zl,
                                             int* __restrict__ cnt, double* __restrict__ psum) {
  int blk = blockIdx.x;
  int t = threadIdx.x;
  if (blk < 1024) {
    // ---- cast_w1 ----
    __shared__ float tile[32][33];
    __shared__ float red[8][33];
    int kb = (blk & 31) << 5, nb = (blk >> 5) << 5;
    int cc = t & 31, rr = t >> 5;
    if (blk == 0 && t < E) { cnt[t] = 0; psum[t] = 0.0; }
#pragma unroll
    for (int r = 0; r < 4; ++r) {
      int k = kb + rr + (r << 3);
      tile[rr + (r << 3)][cc] = w1[(size_t)k * H + nb + cc];
    }
    __syncthreads();
    float pp = 0.f;
#pragma unroll
    for (int r = 0; r < 4; ++r) {
      int kk = rr + (r << 3);
      pp = fmaf(lbi[kb + kk], tile[kk][cc], pp);
    }
    red[rr][cc] = pp;
    float scale = lsc[kb + cc];
    __syncthreads();
    if (rr == 0) {
      float s = 0.f;
#pragma unroll
      for (int j = 0; j < 8; ++j) s += red[j][cc];
      part[(blk & 31) * H + nb + cc] = s;
    }
#pragma unroll
    for (int r = 0; r < 4; ++r) {
      int n = nb + rr + (r << 3);
      float v = tile[cc][rr + (r << 3)] * scale;
      unsigned short h = f2bf(v);
      float hv = __uint_as_float((unsigned)h << 16);
      unsigned short l = f2bf(v - hv);
      w1h[(size_t)n * H + kb + cc] = h;
      w1l[(size_t)n * H + kb + cc] = l;
    }
  } else {
    // ---- stats + casts ----
    int tok = blk - 1024;
    const float4 v = *reinterpret_cast<const float4*>(&x[(size_t)tok * H + (t << 2)]);
    float s = v.x + v.y + v.z + v.w;
    float ss = v.x * v.x + v.y * v.y + v.z * v.z + v.w * v.w;
#pragma unroll
    for (int off = 32; off; off >>= 1) { s += __shfl_down(s, off); ss += __shfl_down(ss, off); }
    __shared__ float red2[4][2];
    int lane = t & 63, wv = t >> 6;
    if (lane == 0) { red2[wv][0] = s; red2[wv][1] = ss; }
    __syncthreads();
    float fs = red2[0][0] + red2[1][0] + red2[2][0] + red2[3][0];
    float fss = red2[0][1] + red2[1][1] + red2[2][1] + red2[3][1];
    float mean = fs * (1.0f / H);
    float var = fss * (1.0f / H) - mean * mean;
    float rstd = rsqrtf(var + 1e-5f);
    float mb = -mean * rstd;
    size_t base = (size_t)tok * H + (t << 2);
    ushort4 ob;
    ob.x = f2bf(v.x); ob.y = f2bf(v.y); ob.z = f2bf(v.z); ob.w = f2bf(v.w);
    *reinterpret_cast<ushort4*>(&xb[base]) = ob;
    // LN + trunc hi/lo split (bitwise-identical to the former in-router split)
    float zz[4];
    zz[0] = fmaf(v.x, rstd, mb); zz[1] = fmaf(v.y, rstd, mb);
    zz[2] = fmaf(v.z, rstd, mb); zz[3] = fmaf(v.w, rstd, mb);
    unsigned u0 = __float_as_uint(zz[0]), u1 = __float_as_uint(zz[1]);
    unsigned u2 = __float_as_uint(zz[2]), u3 = __float_as_uint(zz[3]);
    ushort4 oh, ol;
    oh.x = (unsigned short)(u0 >> 16); oh.y = (unsigned short)(u1 >> 16);
    oh.z = (unsigned short)(u2 >> 16); oh.w = (unsigned short)(u3 >> 16);
    float l0 = zz[0] - __uint_as_float(u0 & 0xffff0000u);
    float l1 = zz[1] - __uint_as_float(u1 & 0xffff0000u);
    float l2 = zz[2] - __uint_as_float(u2 & 0xffff0000u);
    float l3 = zz[3] - __uint_as_float(u3 & 0xffff0000u);
    ol.x = (unsigned short)(__float_as_uint(l0) >> 16); ol.y = (unsigned short)(__float_as_uint(l1) >> 16);
    ol.z = (unsigned short)(__float_as_uint(l2) >> 16); ol.w = (unsigned short)(__float_as_uint(l3) >> 16);
    *reinterpret_cast<ushort4*>(&zh[base]) = oh;
    *reinterpret_cast<ushort4*>(&zl[base]) = ol;
  }
}

// Router GEMM on MFMA: hmid-tile = z @ (lsc*w1) via hi/lo bf16 split (3 passes).
// R3 skeleton (single-buffer, 2 barriers/step, register prefetch, 33 KB LDS -> 4 blocks/CU) with the
// A-path now PURE DATA MOVEMENT: zh/zl int4 register loads -> ds_writes (no per-step LN/split VALU).
// Epilogue computes its own b1eff slice, then relu(tile+b1eff) @ w2 partials -> plog.
__global__ __launch_bounds__(256) void k_router_mfma(
    const unsigned short* __restrict__ zh, const unsigned short* __restrict__ zl,
    const unsigned short* __restrict__ w1h, const unsigned short* __restrict__ w1l,
    const float* __restrict__ part, const float* __restrict__ b1, const float* __restrict__ w2,
    float* __restrict__ plog) {
  __shared__ __align__(16) short Ah[4096], Al[4096], Bh[4096], Bl[4096];
  int t = threadIdx.x;
  int bm = blockIdx.x << 7, bn = blockIdx.y << 7;
  int arow = t >> 1, ac0 = (t & 1) << 1;  // A: 16 bf16 per thread per operand (chunks ac0, ac0+1)
  int brow = t >> 2, bc = t & 3;          // B: rows brow, brow+64, chunk bc
  const unsigned short* za = &zh[(size_t)(bm + arow) * H + (ac0 << 3)];
  const unsigned short* zb = &zl[(size_t)(bm + arow) * H + (ac0 << 3)];
  const unsigned short* s1 = &w1h[(size_t)(bn + brow) * H + (bc << 3)];
  const unsigned short* s2 = &w1h[(size_t)(bn + brow + 64) * H + (bc << 3)];
  const unsigned short* s3 = &w1l[(size_t)(bn + brow) * H + (bc << 3)];
  const unsigned short* s4 = &w1l[(size_t)(bn + brow + 64) * H + (bc << 3)];
  int4 va0 = *(const int4*)za, va1 = *(const int4*)(za + 8);
  int4 va2 = *(const int4*)zb, va3 = *(const int4*)(zb + 8);
  int4 vb0 = *(const int4*)s1, vb1 = *(const int4*)s2, vb2 = *(const int4*)s3, vb3 = *(const int4*)s4;
  int lane = t & 63, wv = t >> 6;
  int wr = (wv >> 1) << 6, wc = (wv & 1) << 6;
  int l15 = lane & 15, lgp = lane >> 4;
  int wA0 = swz(arow, ac0), wA1 = swz(arow, ac0 + 1);
  f32x4 acc[4][4];
#pragma unroll
  for (int i = 0; i < 4; ++i)
#pragma unroll
    for (int j = 0; j < 4; ++j) acc[i][j] = f32x4{0.f, 0.f, 0.f, 0.f};
  for (int kt = 0; kt < 32; ++kt) {
    __syncthreads();  // previous iteration's fragment reads complete
    *(int4*)&Ah[wA0] = va0;
    *(int4*)&Ah[wA1] = va1;
    *(int4*)&Al[wA0] = va2;
    *(int4*)&Al[wA1] = va3;
    *(int4*)&Bh[swz(brow, bc)] = vb0;
    *(int4*)&Bh[swz(brow + 64, bc)] = vb1;
    *(int4*)&Bl[swz(brow, bc)] = vb2;
    *(int4*)&Bl[swz(brow + 64, bc)] = vb3;
    __syncthreads();
    if (kt + 1 < 32) {  // prefetch next k-tile into regs (hides under MFMA)
      za += 32; zb += 32; s1 += 32; s2 += 32; s3 += 32; s4 += 32;
      va0 = *(const int4*)za; va1 = *(const int4*)(za + 8);
      va2 = *(const int4*)zb; va3 = *(const int4*)(zb + 8);
      vb0 = *(const int4*)s1; vb1 = *(const int4*)s2; vb2 = *(const int4*)s3; vb3 = *(const int4*)s4;
    }
    bf16x8 bh[4], bl[4];
#pragma unroll
    for (int j = 0; j < 4; ++j) {
      bh[j] = *(const bf16x8*)&Bh[swz(wc + (j << 4) + l15, lgp)];
      bl[j] = *(const bf16x8*)&Bl[swz(wc + (j << 4) + l15, lgp)];
    }
#pragma unroll
    for (int i = 0; i < 4; ++i) {
      bf16x8 ah = *(const bf16x8*)&Ah[swz(wr + (i << 4) + l15, lgp)];
      bf16x8 al = *(const bf16x8*)&Al[swz(wr + (i << 4) + l15, lgp)];
#pragma unroll
      for (int j = 0; j < 4; ++j) {
        acc[i][j] = __builtin_amdgcn_mfma_f32_16x16x32_bf16(ah, bh[j], acc[i][j], 0, 0, 0);
        acc[i][j] = __builtin_amdgcn_mfma_f32_16x16x32_bf16(ah, bl[j], acc[i][j], 0, 0, 0);
        acc[i][j] = __builtin_amdgcn_mfma_f32_16x16x32_bf16(al, bh[j], acc[i][j], 0, 0, 0);
      }
    }
  }
  // epilogue: per-block b1eff slice (bit-identical order), bias + relu, logits partials
  float w2r[4][8], b1r[4];
#pragma unroll
  for (int j = 0; j < 4; ++j) {
    int col = bn + wc + (j << 4) + l15;
    float4 p0 = *(const float4*)&w2[(size_t)col * E];
    float4 p1 = *(const float4*)&w2[(size_t)col * E + 4];
    w2r[j][0] = p0.x; w2r[j][1] = p0.y; w2r[j][2] = p0.z; w2r[j][3] = p0.w;
    w2r[j][4] = p1.x; w2r[j][5] = p1.y; w2r[j][6] = p1.z; w2r[j][7] = p1.w;
    float s = b1[col];
    for (int jj = 0; jj < 32; ++jj) s += part[jj * H + col];
    b1r[j] = s;
  }
#pragma unroll
  for (int i = 0; i < 4; ++i)
#pragma unroll
    for (int j = 0; j < 4; ++j)
#pragma unroll
      for (int r = 0; r < 4; ++r) acc[i][j][r] = fmaxf(acc[i][j][r] + b1r[j], 0.f);
  int wh = wc >> 6;
  size_t pbase = ((size_t)(blockIdx.y * 2 + wh) * TT + bm) * E;
#pragma unroll
  for (int e = 0; e < E; ++e) {
    float se[4][4];
#pragma unroll
    for (int i = 0; i < 4; ++i)
#pragma unroll
      for (int r = 0; r < 4; ++r)
        se[i][r] = acc[i][0][r] * w2r[0][e] + acc[i][1][r] * w2r[1][e] +
                   acc[i][2][r] * w2r[2][e] + acc[i][3][r] * w2r[3][e];
#pragma unroll
    for (int off = 1; off < 16; off <<= 1)
#pragma unroll
      for (int i = 0; i < 4; ++i)
#pragma unroll
        for (int r = 0; r < 4; ++r) se[i][r] += __shfl_xor(se[i][r], off);
    if (l15 == 0) {
#pragma unroll
      for (int i = 0; i < 4; ++i)
#pragma unroll
        for (int r = 0; r < 4; ++r) {
          int row = wr + (i << 4) + (lgp << 2) + r;
          plog[pbase + (size_t)row * E + e] = se[i][r];
        }
    }
  }
}

// thread-per-token: sum 16 logit partials + b2 -> softmax -> top2 -> renorm; wave-aggregated lists + psum
__global__ __launch_bounds__(256) void k_top(const float* __restrict__ plog, const float* __restrict__ b2,
                                             int* __restrict__ topE, float* __restrict__ topW,
                                             int* __restrict__ listIdx, float* __restrict__ listW,
                                             int* __restrict__ cnt, double* __restrict__ psum) {
  int t = threadIdx.x, lane = t & 63;
  int tok = (blockIdx.x << 8) + t;
  float lg[E], p[E];
  float4 ba = *reinterpret_cast<const float4*>(b2);
  float4 bb = *reinterpret_cast<const float4*>(b2 + 4);
  lg[0] = ba.x; lg[1] = ba.y; lg[2] = ba.z; lg[3] = ba.w;
  lg[4] = bb.x; lg[5] = bb.y; lg[6] = bb.z; lg[7] = bb.w;
#pragma unroll
  for (int nb = 0; nb < 16; ++nb) {
    const float* pp = &plog[((size_t)nb * TT + tok) * E];
    float4 q0 = *reinterpret_cast<const float4*>(pp);
    float4 q1 = *reinterpret_cast<const float4*>(pp + 4);
    lg[0] += q0.x; lg[1] += q0.y; lg[2] += q0.z; lg[3] += q0.w;
    lg[4] += q1.x; lg[5] += q1.y; lg[6] += q1.z; lg[7] += q1.w;
  }
  float m = lg[0];
#pragma unroll
  for (int e = 1; e < E; ++e) m = fmaxf(m, lg[e]);
  float s = 0.f;
#pragma unroll
  for (int e = 0; e < E; ++e) { p[e] = __expf(lg[e] - m); s += p[e]; }
  float inv = 1.f / s;
#pragma unroll
  for (int e = 0; e < E; ++e) p[e] *= inv;
  {
    float ps[E];
#pragma unroll
    for (int e = 0; e < E; ++e) ps[e] = p[e];
#pragma unroll
    for (int off = 1; off < 64; off <<= 1)
#pragma unroll
      for (int e = 0; e < E; ++e) ps[e] += __shfl_xor(ps[e], off);
    if (lane == 0)
#pragma unroll
      for (int e = 0; e < E; ++e) atomicAdd(&psum[e], (double)ps[e]);
  }
  int e0 = 0;
#pragma unroll
  for (int e = 1; e < E; ++e) if (p[e] > p[e0]) e0 = e;  // strict >: first max (jax tie order)
  int e1 = (e0 == 0) ? 1 : 0;
#pragma unroll
  for (int e = 0; e < E; ++e) if (e != e0 && p[e] > p[e1]) e1 = e;
  float rsw = 1.f / (p[e0] + p[e1]);
  float w0 = p[e0] * rsw, w1v = p[e1] * rsw;
  topE[tok << 1] = e0; topE[(tok << 1) + 1] = e1;
  topW[tok << 1] = w0; topW[(tok << 1) + 1] = w1v;
  unsigned long long lt = (1ull << lane) - 1ull;
#pragma unroll
  for (int e = 0; e < E; ++e) {
    unsigned long long m0 = __ballot(e0 == e);
    unsigned long long m1 = __ballot(e1 == e);
    int n0 = __popcll(m0), total = n0 + __popcll(m1);
    if (total == 0) continue;  // wave-uniform
    int leader = __ffsll(m0 | m1) - 1;
    int base = 0;
    if (lane == leader) base = atomicAdd(&cnt[e], total);
    base = __shfl(base, leader);
    if (e0 == e) {
      int pos = e * TT + base + __popcll(m0 & lt);
      listIdx[pos] = (tok << 1); listW[pos] = w0;
    }
    if (e1 == e) {
      int pos = e * TT + base + n0 + __popcll(m1 & lt);
      listIdx[pos] = (tok << 1) | 1; listW[pos] = w1v;
    }
  }
}

// We cast (+ sched in block (0,0,0)): We [E][H][H] f32 -> wet [E][n][k] bf16; work list built once.
// NOTE: wet overlays zh (dead after router); this kernel runs after k_top.
#define WL_SLOTS 2560
__global__ __launch_bounds__(256) void k_cast_we(const float* __restrict__ we, unsigned short* __restrict__ wet,
                                                 const int* __restrict__ cnt, int* __restrict__ workList) {
  __shared__ unsigned short tile[32][33];
  int e = blockIdx.z;
  int kb = blockIdx.x << 5, nb = blockIdx.y << 5;
  int t = threadIdx.x;
  if (blockIdx.x == 0 && blockIdx.y == 0 && blockIdx.z == 0) {
    // sched: runs after k_top (cnt final). item (e,bx,by) at slot g*8+e; overflow region per expert.
    for (int i = t; i < WL_SLOTS; i += 256) workList[i] = -1;
    __syncthreads();
    if (t < E) {
      int ee = t;
      int nbk = (cnt[ee] + 127) >> 7;
      int ov = 2048 + (ee << 6);
      int g = 0;
      for (int bx = 0; bx < nbk; ++bx) {
        for (int by = 0; by < 8; ++by) {
          int item = (ee << 12) | (bx << 4) | by;
          int slot = (g < 256) ? ((g << 3) + ee) : ov++;
          workList[slot] = item;
          ++g;
        }
      }
    }
    __syncthreads();
  }
  int cc = t & 31, rr = t >> 5;
  size_t base = (size_t)e * H * H;
#pragma unroll
  for (int r = 0; r < 4; ++r) {
    int k = kb + rr + (r << 3);
    tile[rr + (r << 3)][cc] = f2bf(we[base + (size_t)k * H + nb + cc]);
  }
  __syncthreads();
#pragma unroll
  for (int r = 0; r < 4; ++r) {
    int n = nb + rr + (r << 3);
    wet[base + (size_t)n * H + kb + cc] = tile[cc][rr + (r << 3)];
  }
}

// grouped bf16 MFMA GEMM via exact work list (measured 97us):
// BM=128, BN=128, BK=32; 4 waves 2x2; A+B gld16 2-buffer (33 KB -> 4 blocks/CU); counted vmcnt(4);
// 2 barriers/step; setprio around MFMA cluster.
__global__ __launch_bounds__(256) void k_expert_gemm(const unsigned short* __restrict__ xb,
                                                     const unsigned short* __restrict__ wet,
                                                     const int* __restrict__ listIdx, const float* __restrict__ listW,
                                                     const int* __restrict__ cnt, const int* __restrict__ workList,
                                                     unsigned short* __restrict__ ys) {
  int item = workList[blockIdx.x];
  if (item < 0) return;
  int e = item >> 12, bx = (item >> 4) & 255, by = item & 15;
  int c = cnt[e];
  int r0 = bx << 7, n0 = by << 7;
  __shared__ __align__(16) short A[2][4096], Bs[2][4096];
  __shared__ int gi[128];
  __shared__ float gw[128];
  int t = threadIdx.x;
  if (t < 128) {
    int rr = r0 + t;
    gi[t] = (rr < c) ? listIdx[e * TT + rr] : -1;
    gw[t] = (rr < c) ? listW[e * TT + rr] : 0.f;
  }
  __syncthreads();
  int w = t >> 6, lane = t & 63;
  int l15 = lane & 15, lgp = lane >> 4;
  int wr = (w >> 1) << 6, wc = (w & 1) << 6;
  // staging: 2 slots/thread per operand, pre-swizzled global chunk
  int s0 = (w << 7) + lane, s1 = s0 + 64;
  int rA0 = s0 >> 2, cg0 = (s0 & 3) ^ ((rA0 >> 1) & 3);
  int rA1 = s1 >> 2, cg1 = (s1 & 3) ^ ((rA1 >> 1) & 3);
  int pk0 = gi[rA0], pk1 = gi[rA1];
  const unsigned short* srcA0 = xb + (size_t)((pk0 < 0) ? 0 : (pk0 >> 1)) * H + (cg0 << 3);
  const unsigned short* srcA1 = xb + (size_t)((pk1 < 0) ? 0 : (pk1 >> 1)) * H + (cg1 << 3);
  size_t wbase = (size_t)e * H * H;
  const unsigned short* srcB0 = wet + wbase + (size_t)(n0 + rA0) * H + (cg0 << 3);
  const unsigned short* srcB1 = wet + wbase + (size_t)(n0 + rA1) * H + (cg1 << 3);
  int d0 = (w << 10), d1 = d0 + 512;  // wave-uniform LDS short offsets
  f32x4 acc[4][4];
#pragma unroll
  for (int i = 0; i < 4; ++i)
#pragma unroll
    for (int j = 0; j < 4; ++j) acc[i][j] = f32x4{0.f, 0.f, 0.f, 0.f};
  // prologue: stage tile 0
  gld16(&A[0][d0], srcA0); gld16(&A[0][d1], srcA1);
  gld16(&Bs[0][d0], srcB0); gld16(&Bs[0][d1], srcB1);
#pragma unroll
  for (int kt = 0; kt < 32; ++kt) {
    const int cur = kt & 1, nxt = cur ^ 1;
    if (kt < 31) {  // issue next tile first; its 4 loads stay in flight across the wait
      const int ko = (kt + 1) << 5;
      gld16(&A[nxt][d0], srcA0 + ko); gld16(&A[nxt][d1], srcA1 + ko);
      gld16(&Bs[nxt][d0], srcB0 + ko); gld16(&Bs[nxt][d1], srcB1 + ko);
      asm volatile("s_waitcnt vmcnt(4)" ::: "memory");  // tile kt landed; kt+1 in flight
    } else {
      asm volatile("s_waitcnt vmcnt(0)" ::: "memory");
    }
    __builtin_amdgcn_sched_barrier(0);
    __builtin_amdgcn_s_barrier();
    __builtin_amdgcn_sched_barrier(0);
    bf16x8 bq[4];
#pragma unroll
    for (int j = 0; j < 4; ++j) bq[j] = *(const bf16x8*)&Bs[cur][swz(wc + (j << 4) + l15, lgp)];
    bf16x8 aq[4];
#pragma unroll
    for (int i = 0; i < 4; ++i) aq[i] = *(const bf16x8*)&A[cur][swz(wr + (i << 4) + l15, lgp)];
    __builtin_amdgcn_s_setprio(1);
#pragma unroll
    for (int i = 0; i < 4; ++i)
#pragma unroll
      for (int j = 0; j < 4; ++j)
        acc[i][j] = __builtin_amdgcn_mfma_f32_16x16x32_bf16(aq[i], bq[j], acc[i][j], 0, 0, 0);
    __builtin_amdgcn_s_setprio(0);
    if (kt < 31) {  // end-of-step: all waves done reading buf cur -> next step may restage it
      __builtin_amdgcn_sched_barrier(0);
      __builtin_amdgcn_s_barrier();
    }
  }
#pragma unroll
  for (int i = 0; i < 4; ++i) {
#pragma unroll
    for (int r = 0; r < 4; ++r) {
      int row = wr + (i << 4) + (lgp << 2) + r;  // C/D: col=lane&15, row=(lane>>4)*4+reg
      int pk = gi[row];
      if (pk < 0) continue;
      int tok = pk >> 1, slot = pk & 1;
      float wgt = gw[row];
      size_t ob = ((size_t)slot * TT + tok) * H + n0 + wc + l15;
#pragma unroll
      for (int j = 0; j < 4; ++j) ys[ob + (j << 4)] = __half_as_ushort(__float2half(wgt * acc[i][j][r]));
    }
  }
}

// out = y_slot0 + y_slot1 + w0*be[e0] + w1*be[e1]; block 0 thread 0 also computes aux.
__global__ __launch_bounds__(256) void k_combine(const unsigned short* __restrict__ ys, const int* __restrict__ topE,
                                                 const float* __restrict__ topW, const float* __restrict__ be,
                                                 const double* __restrict__ psum, float* __restrict__ out) {
  int tok = blockIdx.x, t = threadIdx.x;
  if (tok == 0 && t == 0) {
    double a = 0.0;
    for (int e = 0; e < E; ++e) {
      double mp = psum[e] / (double)TT;
      a += mp * log(mp * (double)E + 1e-9);
    }
    out[(size_t)TT * H] = (float)a;
  }
  int e0 = topE[tok << 1], e1 = topE[(tok << 1) + 1];
  float w0 = topW[tok << 1], w1v = topW[(tok << 1) + 1];
  int h = t << 2;
  size_t base = (size_t)tok * H + h;
  ushort4 a = *reinterpret_cast<const ushort4*>(&ys[base]);
  ushort4 b = *reinterpret_cast<const ushort4*>(&ys[(size_t)TT * H + base]);
  float4 b0 = *reinterpret_cast<const float4*>(&be[e0 * H + h]);
  float4 b1v = *reinterpret_cast<const float4*>(&be[e1 * H + h]);
  float4 o;
  o.x = __half2float(__ushort_as_half(a.x)) + __half2float(__ushort_as_half(b.x)) + w0 * b0.x + w1v * b1v.x;
  o.y = __half2float(__ushort_as_half(a.y)) + __half2float(__ushort_as_half(b.y)) + w0 * b0.y + w1v * b1v.y;
  o.z = __half2float(__ushort_as_half(a.z)) + __half2float(__ushort_as_half(b.z)) + w0 * b0.z + w1v * b1v.z;
  o.w = __half2float(__ushort_as_half(a.w)) + __half2float(__ushort_as_half(b.w)) + w0 * b0.w + w1v * b1v.w;
  *reinterpret_cast<float4*>(&out[base]) = o;
}

extern "C" void kernel_launch(void* const* d_in, const int* in_sizes, int n_in, void* d_out, int out_size, void* d_ws,
                              size_t ws_size, hipStream_t stream) {
  const float* x = (const float*)d_in[0];
  const float* lsc = (const float*)d_in[1];
  const float* lbi = (const float*)d_in[2];
  const float* w1 = (const float*)d_in[3];
  const float* b1 = (const float*)d_in[4];
  const float* w2 = (const float*)d_in[5];
  const float* b2 = (const float*)d_in[6];
  const float* we = (const float*)d_in[7];
  const float* be = (const float*)d_in[8];
  float* out = (float*)d_out;
  char* ws = (char*)d_ws;

  // ws timeline (peak 66 MB):
  // [0,2M): small; [2,18M): xb bf16;
  // [18,34M): zh 16MB (dead after router) -> wet bf16 (written by k_cast_we after k_top);
  // [34,36M): w1h; [36,38M): w1l (dead after router);
  // [38,54M): zl 16MB (dead after router);
  // [54,58M): plog 4MB (16 slices x TT x E f32; dead after k_top);
  // ys fp16 [2][TT][H] = [34,66M) (born at expert; overlays w1h/w1l/zl/plog).
  char* p = ws;
  int* topE = (int*)p; p += TT * 2 * 4;
  float* topW = (float*)p; p += TT * 2 * 4;
  int* listIdx = (int*)p; p += E * TT * 4;
  float* listW = (float*)p; p += E * TT * 4;
  int* cnt = (int*)p; p += 256;
  double* psum = (double*)p; p += 2048;
  float* part = (float*)p; p += 32 * H * 4;
  int* workList = (int*)p; p += WL_SLOTS * 4;
  unsigned short* xb = (unsigned short*)(ws + (2ull << 20));
  unsigned short* zh = (unsigned short*)(ws + (18ull << 20));
  unsigned short* wet = (unsigned short*)(ws + (18ull << 20));  // overlays zh (after router)
  unsigned short* w1h = (unsigned short*)(ws + (34ull << 20));
  unsigned short* w1l = (unsigned short*)(ws + (36ull << 20));
  unsigned short* zl = (unsigned short*)(ws + (38ull << 20));
  float* plog = (float*)(ws + (54ull << 20));
  unsigned short* ys = (unsigned short*)(ws + (34ull << 20));  // overlays w1h/w1l/zl/plog (after k_top)

  k_pre<<<1024 + TT, 256, 0, stream>>>(w1, lsc, lbi, x, w1h, w1l, part, xb, zh, zl, cnt, psum);
  k_router_mfma<<<dim3(TT / 128, H / 128), 256, 0, stream>>>(zh, zl, w1h, w1l, part, b1, w2, plog);
  k_top<<<TT / 256, 256, 0, stream>>>(plog, b2, topE, topW, listIdx, listW, cnt, psum);
  k_cast_we<<<dim3(32, 32, E), 256, 0, stream>>>(we, wet, cnt, workList);
  k_expert_gemm<<<WL_SLOTS, 256, 0, stream>>>(xb, wet, listIdx, listW, cnt, workList, ys);
  k_combine<<<TT, 256, 0, stream>>>(ys, topE, topW, be, psum, out);
}

// Round 19
// 202.518 us; speedup vs baseline: 1.0717x; 1.0009x over previous
//
#include <hip/hip_runtime.h>
#include <hip/hip_fp16.h>

#define H 1024
#define E 8
#define TT 8192  // tokens = B*S

typedef __attribute__((ext_vector_type(8))) short bf16x8;
typedef __attribute__((ext_vector_type(4))) float f32x4;

__device__ __forceinline__ unsigned short f2bf(float f) {
  unsigned int u = __float_as_uint(f);
  u += 0x7fffu + ((u >> 16) & 1u);
  return (unsigned short)(u >> 16);
}

// LDS tile addressing: rows of 32 bf16 = 64B = 4 chunks of 16B.
// XOR swizzle chunk' = c ^ ((row>>1)&3): conflict-free writes AND mfma b128 reads (0 conflicts, R3-R18).
__device__ __forceinline__ int swz(int row, int c) {
  return (row << 5) | (((c ^ (row >> 1)) & 3) << 3);
}

// async global->LDS, 16B per lane; LDS dest = wave-uniform base + lane*16 (linear).
__device__ __forceinline__ void gld16(void* lds, const void* g) {
  __builtin_amdgcn_global_load_lds((const __attribute__((address_space(1))) void*)g,
                                   (__attribute__((address_space(3))) void*)lds, 16, 0, 0);
}

// Fused roots: blocks [0,1024) = cast_w1 (+part partials, +init cnt/psum);
// blocks [1024,9216) = stats -> xb (rounded bf16 of raw x) AND zh/zl (trunc hi/lo split of LN(x)).
__global__ __launch_bounds__(256) void k_pre(const float* __restrict__ w1, const float* __restrict__ lsc,
                                             const float* __restrict__ lbi, const float* __restrict__ x,
                                             unsigned short* __restrict__ w1h, unsigned short* __restrict__ w1l,
                                             float* __restrict__ part, unsigned short* __restrict__ xb,
                                             unsigned short* __restrict__ zh, unsigned short* __restrict__ zl,
                                             int* __restrict__ cnt, double* __restrict__ psum) {
  int blk = blockIdx.x;
  int t = threadIdx.x;
  if (blk < 1024) {
    // ---- cast_w1 ----
    __shared__ float tile[32][33];
    __shared__ float red[8][33];
    int kb = (blk & 31) << 5, nb = (blk >> 5) << 5;
    int cc = t & 31, rr = t >> 5;
    if (blk == 0 && t < E) { cnt[t] = 0; psum[t] = 0.0; }
#pragma unroll
    for (int r = 0; r < 4; ++r) {
      int k = kb + rr + (r << 3);
      tile[rr + (r << 3)][cc] = w1[(size_t)k * H + nb + cc];
    }
    __syncthreads();
    float pp = 0.f;
#pragma unroll
    for (int r = 0; r < 4; ++r) {
      int kk = rr + (r << 3);
      pp = fmaf(lbi[kb + kk], tile[kk][cc], pp);
    }
    red[rr][cc] = pp;
    float scale = lsc[kb + cc];
    __syncthreads();
    if (rr == 0) {
      float s = 0.f;
#pragma unroll
      for (int j = 0; j < 8; ++j) s += red[j][cc];
      part[(blk & 31) * H + nb + cc] = s;
    }
#pragma unroll
    for (int r = 0; r < 4; ++r) {
      int n = nb + rr + (r << 3);
      float v = tile[cc][rr + (r << 3)] * scale;
      unsigned short h = f2bf(v);
      float hv = __uint_as_float((unsigned)h << 16);
      unsigned short l = f2bf(v - hv);
      w1h[(size_t)n * H + kb + cc] = h;
      w1l[(size_t)n * H + kb + cc] = l;
    }
  } else {
    // ---- stats + casts ----
    int tok = blk - 1024;
    const float4 v = *reinterpret_cast<const float4*>(&x[(size_t)tok * H + (t << 2)]);
    float s = v.x + v.y + v.z + v.w;
    float ss = v.x * v.x + v.y * v.y + v.z * v.z + v.w * v.w;
#pragma unroll
    for (int off = 32; off; off >>= 1) { s += __shfl_down(s, off); ss += __shfl_down(ss, off); }
    __shared__ float red2[4][2];
    int lane = t & 63, wv = t >> 6;
    if (lane == 0) { red2[wv][0] = s; red2[wv][1] = ss; }
    __syncthreads();
    float fs = red2[0][0] + red2[1][0] + red2[2][0] + red2[3][0];
    float fss = red2[0][1] + red2[1][1] + red2[2][1] + red2[3][1];
    float mean = fs * (1.0f / H);
    float var = fss * (1.0f / H) - mean * mean;
    float rstd = rsqrtf(var + 1e-5f);
    float mb = -mean * rstd;
    size_t base = (size_t)tok * H + (t << 2);
    ushort4 ob;
    ob.x = f2bf(v.x); ob.y = f2bf(v.y); ob.z = f2bf(v.z); ob.w = f2bf(v.w);
    *reinterpret_cast<ushort4*>(&xb[base]) = ob;
    // LN + trunc hi/lo split (bitwise-identical to the former in-router split)
    float zz[4];
    zz[0] = fmaf(v.x, rstd, mb); zz[1] = fmaf(v.y, rstd, mb);
    zz[2] = fmaf(v.z, rstd, mb); zz[3] = fmaf(v.w, rstd, mb);
    unsigned u0 = __float_as_uint(zz[0]), u1 = __float_as_uint(zz[1]);
    unsigned u2 = __float_as_uint(zz[2]), u3 = __float_as_uint(zz[3]);
    ushort4 oh, ol;
    oh.x = (unsigned short)(u0 >> 16); oh.y = (unsigned short)(u1 >> 16);
    oh.z = (unsigned short)(u2 >> 16); oh.w = (unsigned short)(u3 >> 16);
    float l0 = zz[0] - __uint_as_float(u0 & 0xffff0000u);
    float l1 = zz[1] - __uint_as_float(u1 & 0xffff0000u);
    float l2 = zz[2] - __uint_as_float(u2 & 0xffff0000u);
    float l3 = zz[3] - __uint_as_float(u3 & 0xffff0000u);
    ol.x = (unsigned short)(__float_as_uint(l0) >> 16); ol.y = (unsigned short)(__float_as_uint(l1) >> 16);
    ol.z = (unsigned short)(__float_as_uint(l2) >> 16); ol.w = (unsigned short)(__float_as_uint(l3) >> 16);
    *reinterpret_cast<ushort4*>(&zh[base]) = oh;
    *reinterpret_cast<ushort4*>(&zl[base]) = ol;
  }
}

// Router GEMM on MFMA: hmid-tile = z @ (lsc*w1) via hi/lo bf16 split (3 passes).
// R3 skeleton (single-buffer, 2 barriers/step, register prefetch, 33 KB LDS -> 4 blocks/CU) with the
// A-path PURE DATA MOVEMENT: zh/zl int4 register loads -> ds_writes (no per-step LN/split VALU).
// Epilogue computes its own b1eff slice, then relu(tile+b1eff) @ w2 partials -> plog.
__global__ __launch_bounds__(256) void k_router_mfma(
    const unsigned short* __restrict__ zh, const unsigned short* __restrict__ zl,
    const unsigned short* __restrict__ w1h, const unsigned short* __restrict__ w1l,
    const float* __restrict__ part, const float* __restrict__ b1, const float* __restrict__ w2,
    float* __restrict__ plog) {
  __shared__ __align__(16) short Ah[4096], Al[4096], Bh[4096], Bl[4096];
  int t = threadIdx.x;
  int bm = blockIdx.x << 7, bn = blockIdx.y << 7;
  int arow = t >> 1, ac0 = (t & 1) << 1;  // A: 16 bf16 per thread per operand (chunks ac0, ac0+1)
  int brow = t >> 2, bc = t & 3;          // B: rows brow, brow+64, chunk bc
  const unsigned short* za = &zh[(size_t)(bm + arow) * H + (ac0 << 3)];
  const unsigned short* zb = &zl[(size_t)(bm + arow) * H + (ac0 << 3)];
  const unsigned short* s1 = &w1h[(size_t)(bn + brow) * H + (bc << 3)];
  const unsigned short* s2 = &w1h[(size_t)(bn + brow + 64) * H + (bc << 3)];
  const unsigned short* s3 = &w1l[(size_t)(bn + brow) * H + (bc << 3)];
  const unsigned short* s4 = &w1l[(size_t)(bn + brow + 64) * H + (bc << 3)];
  int4 va0 = *(const int4*)za, va1 = *(const int4*)(za + 8);
  int4 va2 = *(const int4*)zb, va3 = *(const int4*)(zb + 8);
  int4 vb0 = *(const int4*)s1, vb1 = *(const int4*)s2, vb2 = *(const int4*)s3, vb3 = *(const int4*)s4;
  int lane = t & 63, wv = t >> 6;
  int wr = (wv >> 1) << 6, wc = (wv & 1) << 6;
  int l15 = lane & 15, lgp = lane >> 4;
  int wA0 = swz(arow, ac0), wA1 = swz(arow, ac0 + 1);
  f32x4 acc[4][4];
#pragma unroll
  for (int i = 0; i < 4; ++i)
#pragma unroll
    for (int j = 0; j < 4; ++j) acc[i][j] = f32x4{0.f, 0.f, 0.f, 0.f};
  for (int kt = 0; kt < 32; ++kt) {
    __syncthreads();  // previous iteration's fragment reads complete
    *(int4*)&Ah[wA0] = va0;
    *(int4*)&Ah[wA1] = va1;
    *(int4*)&Al[wA0] = va2;
    *(int4*)&Al[wA1] = va3;
    *(int4*)&Bh[swz(brow, bc)] = vb0;
    *(int4*)&Bh[swz(brow + 64, bc)] = vb1;
    *(int4*)&Bl[swz(brow, bc)] = vb2;
    *(int4*)&Bl[swz(brow + 64, bc)] = vb3;
    __syncthreads();
    if (kt + 1 < 32) {  // prefetch next k-tile into regs (hides under MFMA)
      za += 32; zb += 32; s1 += 32; s2 += 32; s3 += 32; s4 += 32;
      va0 = *(const int4*)za; va1 = *(const int4*)(za + 8);
      va2 = *(const int4*)zb; va3 = *(const int4*)(zb + 8);
      vb0 = *(const int4*)s1; vb1 = *(const int4*)s2; vb2 = *(const int4*)s3; vb3 = *(const int4*)s4;
    }
    bf16x8 bh[4], bl[4];
#pragma unroll
    for (int j = 0; j < 4; ++j) {
      bh[j] = *(const bf16x8*)&Bh[swz(wc + (j << 4) + l15, lgp)];
      bl[j] = *(const bf16x8*)&Bl[swz(wc + (j << 4) + l15, lgp)];
    }
#pragma unroll
    for (int i = 0; i < 4; ++i) {
      bf16x8 ah = *(const bf16x8*)&Ah[swz(wr + (i << 4) + l15, lgp)];
      bf16x8 al = *(const bf16x8*)&Al[swz(wr + (i << 4) + l15, lgp)];
#pragma unroll
      for (int j = 0; j < 4; ++j) {
        acc[i][j] = __builtin_amdgcn_mfma_f32_16x16x32_bf16(ah, bh[j], acc[i][j], 0, 0, 0);
        acc[i][j] = __builtin_amdgcn_mfma_f32_16x16x32_bf16(ah, bl[j], acc[i][j], 0, 0, 0);
        acc[i][j] = __builtin_amdgcn_mfma_f32_16x16x32_bf16(al, bh[j], acc[i][j], 0, 0, 0);
      }
    }
  }
  // epilogue: per-block b1eff slice (bit-identical order), bias + relu, logits partials
  float w2r[4][8], b1r[4];
#pragma unroll
  for (int j = 0; j < 4; ++j) {
    int col = bn + wc + (j << 4) + l15;
    float4 p0 = *(const float4*)&w2[(size_t)col * E];
    float4 p1 = *(const float4*)&w2[(size_t)col * E + 4];
    w2r[j][0] = p0.x; w2r[j][1] = p0.y; w2r[j][2] = p0.z; w2r[j][3] = p0.w;
    w2r[j][4] = p1.x; w2r[j][5] = p1.y; w2r[j][6] = p1.z; w2r[j][7] = p1.w;
    float s = b1[col];
    for (int jj = 0; jj < 32; ++jj) s += part[jj * H + col];
    b1r[j] = s;
  }
#pragma unroll
  for (int i = 0; i < 4; ++i)
#pragma unroll
    for (int j = 0; j < 4; ++j)
#pragma unroll
      for (int r = 0; r < 4; ++r) acc[i][j][r] = fmaxf(acc[i][j][r] + b1r[j], 0.f);
  int wh = wc >> 6;
  size_t pbase = ((size_t)(blockIdx.y * 2 + wh) * TT + bm) * E;
#pragma unroll
  for (int e = 0; e < E; ++e) {
    float se[4][4];
#pragma unroll
    for (int i = 0; i < 4; ++i)
#pragma unroll
      for (int r = 0; r < 4; ++r)
        se[i][r] = acc[i][0][r] * w2r[0][e] + acc[i][1][r] * w2r[1][e] +
                   acc[i][2][r] * w2r[2][e] + acc[i][3][r] * w2r[3][e];
#pragma unroll
    for (int off = 1; off < 16; off <<= 1)
#pragma unroll
      for (int i = 0; i < 4; ++i)
#pragma unroll
        for (int r = 0; r < 4; ++r) se[i][r] += __shfl_xor(se[i][r], off);
    if (l15 == 0) {
#pragma unroll
      for (int i = 0; i < 4; ++i)
#pragma unroll
        for (int r = 0; r < 4; ++r) {
          int row = wr + (i << 4) + (lgp << 2) + r;
          plog[pbase + (size_t)row * E + e] = se[i][r];
        }
    }
  }
}

// thread-per-token: sum 16 logit partials + b2 -> softmax -> top2 -> renorm; wave-aggregated lists + psum
__global__ __launch_bounds__(256) void k_top(const float* __restrict__ plog, const float* __restrict__ b2,
                                             int* __restrict__ topE, float* __restrict__ topW,
                                             int* __restrict__ listIdx, float* __restrict__ listW,
                                             int* __restrict__ cnt, double* __restrict__ psum) {
  int t = threadIdx.x, lane = t & 63;
  int tok = (blockIdx.x << 8) + t;
  float lg[E], p[E];
  float4 ba = *reinterpret_cast<const float4*>(b2);
  float4 bb = *reinterpret_cast<const float4*>(b2 + 4);
  lg[0] = ba.x; lg[1] = ba.y; lg[2] = ba.z; lg[3] = ba.w;
  lg[4] = bb.x; lg[5] = bb.y; lg[6] = bb.z; lg[7] = bb.w;
#pragma unroll
  for (int nb = 0; nb < 16; ++nb) {
    const float* pp = &plog[((size_t)nb * TT + tok) * E];
    float4 q0 = *reinterpret_cast<const float4*>(pp);
    float4 q1 = *reinterpret_cast<const float4*>(pp + 4);
    lg[0] += q0.x; lg[1] += q0.y; lg[2] += q0.z; lg[3] += q0.w;
    lg[4] += q1.x; lg[5] += q1.y; lg[6] += q1.z; lg[7] += q1.w;
  }
  float m = lg[0];
#pragma unroll
  for (int e = 1; e < E; ++e) m = fmaxf(m, lg[e]);
  float s = 0.f;
#pragma unroll
  for (int e = 0; e < E; ++e) { p[e] = __expf(lg[e] - m); s += p[e]; }
  float inv = 1.f / s;
#pragma unroll
  for (int e = 0; e < E; ++e) p[e] *= inv;
  {
    float ps[E];
#pragma unroll
    for (int e = 0; e < E; ++e) ps[e] = p[e];
#pragma unroll
    for (int off = 1; off < 64; off <<= 1)
#pragma unroll
      for (int e = 0; e < E; ++e) ps[e] += __shfl_xor(ps[e], off);
    if (lane == 0)
#pragma unroll
      for (int e = 0; e < E; ++e) atomicAdd(&psum[e], (double)ps[e]);
  }
  int e0 = 0;
#pragma unroll
  for (int e = 1; e < E; ++e) if (p[e] > p[e0]) e0 = e;  // strict >: first max (jax tie order)
  int e1 = (e0 == 0) ? 1 : 0;
#pragma unroll
  for (int e = 0; e < E; ++e) if (e != e0 && p[e] > p[e1]) e1 = e;
  float rsw = 1.f / (p[e0] + p[e1]);
  float w0 = p[e0] * rsw, w1v = p[e1] * rsw;
  topE[tok << 1] = e0; topE[(tok << 1) + 1] = e1;
  topW[tok << 1] = w0; topW[(tok << 1) + 1] = w1v;
  unsigned long long lt = (1ull << lane) - 1ull;
#pragma unroll
  for (int e = 0; e < E; ++e) {
    unsigned long long m0 = __ballot(e0 == e);
    unsigned long long m1 = __ballot(e1 == e);
    int n0 = __popcll(m0), total = n0 + __popcll(m1);
    if (total == 0) continue;  // wave-uniform
    int leader = __ffsll(m0 | m1) - 1;
    int base = 0;
    if (lane == leader) base = atomicAdd(&cnt[e], total);
    base = __shfl(base, leader);
    if (e0 == e) {
      int pos = e * TT + base + __popcll(m0 & lt);
      listIdx[pos] = (tok << 1); listW[pos] = w0;
    }
    if (e1 == e) {
      int pos = e * TT + base + n0 + __popcll(m1 & lt);
      listIdx[pos] = (tok << 1) | 1; listW[pos] = w1v;
    }
  }
}

// We cast (+ sched in block (0,0,0)): We [E][H][H] f32 -> wet [E][n][k] bf16; work list built once.
// NOTE: wet overlays zh (dead after router); this kernel runs after k_top.
#define WL_SLOTS 2560
__global__ __launch_bounds__(256) void k_cast_we(const float* __restrict__ we, unsigned short* __restrict__ wet,
                                                 const int* __restrict__ cnt, int* __restrict__ workList) {
  __shared__ unsigned short tile[32][33];
  int e = blockIdx.z;
  int kb = blockIdx.x << 5, nb = blockIdx.y << 5;
  int t = threadIdx.x;
  if (blockIdx.x == 0 && blockIdx.y == 0 && blockIdx.z == 0) {
    // sched: runs after k_top (cnt final). item (e,bx,by) at slot g*8+e; overflow region per expert.
    for (int i = t; i < WL_SLOTS; i += 256) workList[i] = -1;
    __syncthreads();
    if (t < E) {
      int ee = t;
      int nbk = (cnt[ee] + 127) >> 7;
      int ov = 2048 + (ee << 6);
      int g = 0;
      for (int bx = 0; bx < nbk; ++bx) {
        for (int by = 0; by < 8; ++by) {
          int item = (ee << 12) | (bx << 4) | by;
          int slot = (g < 256) ? ((g << 3) + ee) : ov++;
          workList[slot] = item;
          ++g;
        }
      }
    }
    __syncthreads();
  }
  int cc = t & 31, rr = t >> 5;
  size_t base = (size_t)e * H * H;
#pragma unroll
  for (int r = 0; r < 4; ++r) {
    int k = kb + rr + (r << 3);
    tile[rr + (r << 3)][cc] = f2bf(we[base + (size_t)k * H + nb + cc]);
  }
  __syncthreads();
#pragma unroll
  for (int r = 0; r < 4; ++r) {
    int n = nb + rr + (r << 3);
    wet[base + (size_t)n * H + kb + cc] = tile[cc][rr + (r << 3)];
  }
}

// grouped bf16 MFMA GEMM via exact work list (measured 97us):
// BM=128, BN=128, BK=32; 4 waves 2x2; A+B gld16 2-buffer (33 KB -> 4 blocks/CU); counted vmcnt(4);
// 2 barriers/step; setprio around MFMA cluster.
__global__ __launch_bounds__(256) void k_expert_gemm(const unsigned short* __restrict__ xb,
                                                     const unsigned short* __restrict__ wet,
                                                     const int* __restrict__ listIdx, const float* __restrict__ listW,
                                                     const int* __restrict__ cnt, const int* __restrict__ workList,
                                                     unsigned short* __restrict__ ys) {
  int item = workList[blockIdx.x];
  if (item < 0) return;
  int e = item >> 12, bx = (item >> 4) & 255, by = item & 15;
  int c = cnt[e];
  int r0 = bx << 7, n0 = by << 7;
  __shared__ __align__(16) short A[2][4096], Bs[2][4096];
  __shared__ int gi[128];
  __shared__ float gw[128];
  int t = threadIdx.x;
  if (t < 128) {
    int rr = r0 + t;
    gi[t] = (rr < c) ? listIdx[e * TT + rr] : -1;
    gw[t] = (rr < c) ? listW[e * TT + rr] : 0.f;
  }
  __syncthreads();
  int w = t >> 6, lane = t & 63;
  int l15 = lane & 15, lgp = lane >> 4;
  int wr = (w >> 1) << 6, wc = (w & 1) << 6;
  // staging: 2 slots/thread per operand, pre-swizzled global chunk
  int s0 = (w << 7) + lane, s1 = s0 + 64;
  int rA0 = s0 >> 2, cg0 = (s0 & 3) ^ ((rA0 >> 1) & 3);
  int rA1 = s1 >> 2, cg1 = (s1 & 3) ^ ((rA1 >> 1) & 3);
  int pk0 = gi[rA0], pk1 = gi[rA1];
  const unsigned short* srcA0 = xb + (size_t)((pk0 < 0) ? 0 : (pk0 >> 1)) * H + (cg0 << 3);
  const unsigned short* srcA1 = xb + (size_t)((pk1 < 0) ? 0 : (pk1 >> 1)) * H + (cg1 << 3);
  size_t wbase = (size_t)e * H * H;
  const unsigned short* srcB0 = wet + wbase + (size_t)(n0 + rA0) * H + (cg0 << 3);
  const unsigned short* srcB1 = wet + wbase + (size_t)(n0 + rA1) * H + (cg1 << 3);
  int d0 = (w << 10), d1 = d0 + 512;  // wave-uniform LDS short offsets
  f32x4 acc[4][4];
#pragma unroll
  for (int i = 0; i < 4; ++i)
#pragma unroll
    for (int j = 0; j < 4; ++j) acc[i][j] = f32x4{0.f, 0.f, 0.f, 0.f};
  // prologue: stage tile 0
  gld16(&A[0][d0], srcA0); gld16(&A[0][d1], srcA1);
  gld16(&Bs[0][d0], srcB0); gld16(&Bs[0][d1], srcB1);
#pragma unroll
  for (int kt = 0; kt < 32; ++kt) {
    const int cur = kt & 1, nxt = cur ^ 1;
    if (kt < 31) {  // issue next tile first; its 4 loads stay in flight across the wait
      const int ko = (kt + 1) << 5;
      gld16(&A[nxt][d0], srcA0 + ko); gld16(&A[nxt][d1], srcA1 + ko);
      gld16(&Bs[nxt][d0], srcB0 + ko); gld16(&Bs[nxt][d1], srcB1 + ko);
      asm volatile("s_waitcnt vmcnt(4)" ::: "memory");  // tile kt landed; kt+1 in flight
    } else {
      asm volatile("s_waitcnt vmcnt(0)" ::: "memory");
    }
    __builtin_amdgcn_sched_barrier(0);
    __builtin_amdgcn_s_barrier();
    __builtin_amdgcn_sched_barrier(0);
    bf16x8 bq[4];
#pragma unroll
    for (int j = 0; j < 4; ++j) bq[j] = *(const bf16x8*)&Bs[cur][swz(wc + (j << 4) + l15, lgp)];
    bf16x8 aq[4];
#pragma unroll
    for (int i = 0; i < 4; ++i) aq[i] = *(const bf16x8*)&A[cur][swz(wr + (i << 4) + l15, lgp)];
    __builtin_amdgcn_s_setprio(1);
#pragma unroll
    for (int i = 0; i < 4; ++i)
#pragma unroll
      for (int j = 0; j < 4; ++j)
        acc[i][j] = __builtin_amdgcn_mfma_f32_16x16x32_bf16(aq[i], bq[j], acc[i][j], 0, 0, 0);
    __builtin_amdgcn_s_setprio(0);
    if (kt < 31) {  // end-of-step: all waves done reading buf cur -> next step may restage it
      __builtin_amdgcn_sched_barrier(0);
      __builtin_amdgcn_s_barrier();
    }
  }
#pragma unroll
  for (int i = 0; i < 4; ++i) {
#pragma unroll
    for (int r = 0; r < 4; ++r) {
      int row = wr + (i << 4) + (lgp << 2) + r;  // C/D: col=lane&15, row=(lane>>4)*4+reg
      int pk = gi[row];
      if (pk < 0) continue;
      int tok = pk >> 1, slot = pk & 1;
      float wgt = gw[row];
      size_t ob = ((size_t)slot * TT + tok) * H + n0 + wc + l15;
#pragma unroll
      for (int j = 0; j < 4; ++j) ys[ob + (j << 4)] = __half_as_ushort(__float2half(wgt * acc[i][j][r]));
    }
  }
}

// out = y_slot0 + y_slot1 + w0*be[e0] + w1*be[e1]; block 0 thread 0 also computes aux.
__global__ __launch_bounds__(256) void k_combine(const unsigned short* __restrict__ ys, const int* __restrict__ topE,
                                                 const float* __restrict__ topW, const float* __restrict__ be,
                                                 const double* __restrict__ psum, float* __restrict__ out) {
  int tok = blockIdx.x, t = threadIdx.x;
  if (tok == 0 && t == 0) {
    double a = 0.0;
    for (int e = 0; e < E; ++e) {
      double mp = psum[e] / (double)TT;
      a += mp * log(mp * (double)E + 1e-9);
    }
    out[(size_t)TT * H] = (float)a;
  }
  int e0 = topE[tok << 1], e1 = topE[(tok << 1) + 1];
  float w0 = topW[tok << 1], w1v = topW[(tok << 1) + 1];
  int h = t << 2;
  size_t base = (size_t)tok * H + h;
  ushort4 a = *reinterpret_cast<const ushort4*>(&ys[base]);
  ushort4 b = *reinterpret_cast<const ushort4*>(&ys[(size_t)TT * H + base]);
  float4 b0 = *reinterpret_cast<const float4*>(&be[e0 * H + h]);
  float4 b1v = *reinterpret_cast<const float4*>(&be[e1 * H + h]);
  float4 o;
  o.x = __half2float(__ushort_as_half(a.x)) + __half2float(__ushort_as_half(b.x)) + w0 * b0.x + w1v * b1v.x;
  o.y = __half2float(__ushort_as_half(a.y)) + __half2float(__ushort_as_half(b.y)) + w0 * b0.y + w1v * b1v.y;
  o.z = __half2float(__ushort_as_half(a.z)) + __half2float(__ushort_as_half(b.z)) + w0 * b0.z + w1v * b1v.z;
  o.w = __half2float(__ushort_as_half(a.w)) + __half2float(__ushort_as_half(b.w)) + w0 * b0.w + w1v * b1v.w;
  *reinterpret_cast<float4*>(&out[base]) = o;
}

extern "C" void kernel_launch(void* const* d_in, const int* in_sizes, int n_in, void* d_out, int out_size, void* d_ws,
                              size_t ws_size, hipStream_t stream) {
  const float* x = (const float*)d_in[0];
  const float* lsc = (const float*)d_in[1];
  const float* lbi = (const float*)d_in[2];
  const float* w1 = (const float*)d_in[3];
  const float* b1 = (const float*)d_in[4];
  const float* w2 = (const float*)d_in[5];
  const float* b2 = (const float*)d_in[6];
  const float* we = (const float*)d_in[7];
  const float* be = (const float*)d_in[8];
  float* out = (float*)d_out;
  char* ws = (char*)d_ws;

  // ws timeline (peak 66 MB):
  // [0,2M): small; [2,18M): xb bf16;
  // [18,34M): zh 16MB (dead after router) -> wet bf16 (written by k_cast_we after k_top);
  // [34,36M): w1h; [36,38M): w1l (dead after router);
  // [38,54M): zl 16MB (dead after router);
  // [54,58M): plog 4MB (16 slices x TT x E f32; dead after k_top);
  // ys fp16 [2][TT][H] = [34,66M) (born at expert; overlays w1h/w1l/zl/plog).
  char* p = ws;
  int* topE = (int*)p; p += TT * 2 * 4;
  float* topW = (float*)p; p += TT * 2 * 4;
  int* listIdx = (int*)p; p += E * TT * 4;
  float* listW = (float*)p; p += E * TT * 4;
  int* cnt = (int*)p; p += 256;
  double* psum = (double*)p; p += 2048;
  float* part = (float*)p; p += 32 * H * 4;
  int* workList = (int*)p; p += WL_SLOTS * 4;
  unsigned short* xb = (unsigned short*)(ws + (2ull << 20));
  unsigned short* zh = (unsigned short*)(ws + (18ull << 20));
  unsigned short* wet = (unsigned short*)(ws + (18ull << 20));  // overlays zh (after router)
  unsigned short* w1h = (unsigned short*)(ws + (34ull << 20));
  unsigned short* w1l = (unsigned short*)(ws + (36ull << 20));
  unsigned short* zl = (unsigned short*)(ws + (38ull << 20));
  float* plog = (float*)(ws + (54ull << 20));
  unsigned short* ys = (unsigned short*)(ws + (34ull << 20));  // overlays w1h/w1l/zl/plog (after k_top)

  k_pre<<<1024 + TT, 256, 0, stream>>>(w1, lsc, lbi, x, w1h, w1l, part, xb, zh, zl, cnt, psum);
  k_router_mfma<<<dim3(TT / 128, H / 128), 256, 0, stream>>>(zh, zl, w1h, w1l, part, b1, w2, plog);
  k_top<<<TT / 256, 256, 0, stream>>>(plog, b2, topE, topW, listIdx, listW, cnt, psum);
  k_cast_we<<<dim3(32, 32, E), 256, 0, stream>>>(we, wet, cnt, workList);
  k_expert_gemm<<<WL_SLOTS, 256, 0, stream>>>(xb, wet, listIdx, listW, cnt, workList, ys);
  k_combine<<<TT, 256, 0, stream>>>(ys, topE, topW, be, psum, out);
}